// Round 10
// baseline (61750.476 us; speedup 1.0000x reference)
//
#include <hip/hip_runtime.h>
#include <math.h>

// Round 10: R7 verbatim EXCEPT the barrier wait spin is SLEEPLESS.
// Theory: s_sleep wave-wakeup quantum is µs-scale -> every prior barrier
// variant shared a ~9µs/step floor. With 1 WG/CU, tight spinning is free
// (the polling wave is alone on its SIMD).

#define T_    800
#define B_    16
#define FEAT_ 120
#define H_    512
#define H2_   1024
#define H4_   2048
#define CC_   5000
#define NL_   100
#define CH_   50

typedef __attribute__((ext_vector_type(8))) short bf16x8;
typedef __attribute__((ext_vector_type(4))) float f32x4;

// ---------------- coherent helpers ----------------
__device__ __forceinline__ void coh_store_f32(float* p, float v) {
  asm volatile("global_store_dword %0, %1, off sc0 sc1"
               :: "v"(p), "v"(v) : "memory");
}
__device__ __forceinline__ f32x4 coh_load_f4(const float* p) {
  f32x4 v;
  asm volatile("global_load_dwordx4 %0, %1, off sc0 sc1\n\t"
               "s_waitcnt vmcnt(0)"
               : "=&v"(v) : "v"(p) : "memory");
  return v;
}

// ---------------- bf16 MFMA GEMM (unchanged) ----------------
#define GBM 128
#define GBN 128
#define GBK 32
#define LDT 40

__device__ __forceinline__ unsigned short f2bf(float f) {
  unsigned u = __builtin_bit_cast(unsigned, f);
  u += 0x7FFFu + ((u >> 16) & 1u);
  return (unsigned short)(u >> 16);
}

__device__ __forceinline__ void mfma_gemm_body(
    const float* __restrict__ A, const float* __restrict__ W,
    const float* __restrict__ bias, float* __restrict__ C,
    int M, int N, int K, int ldc)
{
  __shared__ unsigned short As[GBM * LDT];
  __shared__ unsigned short Ws[GBN * LDT];
  const int tid = threadIdx.x;
  const int row0 = blockIdx.y * GBM, col0 = blockIdx.x * GBN;
  const int lane = tid & 63, w = tid >> 6;
  const int wr = w >> 1, wc = w & 1;
  const int lm = lane & 15, lk8 = (lane >> 4) * 8;

  f32x4 acc[4][4];
#pragma unroll
  for (int i = 0; i < 4; i++)
#pragma unroll
    for (int j = 0; j < 4; j++) acc[i][j] = (f32x4)(0.f);

  const int sr = tid >> 1, skh = (tid & 1) * 16;

  for (int kt = 0; kt < K; kt += GBK) {
    {
      const int ar = row0 + sr;
      const int wrow = col0 + sr;
      unsigned short abuf[16], wbuf[16];
#pragma unroll
      for (int q = 0; q < 4; q++) {
        const int k0 = kt + skh + q * 4;
        float4 av = make_float4(0.f, 0.f, 0.f, 0.f);
        float4 wv = make_float4(0.f, 0.f, 0.f, 0.f);
        if (k0 + 4 <= K) {
          if (ar < M)   av = *(const float4*)(A + (size_t)ar * K + k0);
          if (wrow < N) wv = *(const float4*)(W + (size_t)wrow * K + k0);
        }
        abuf[q*4+0] = f2bf(av.x); abuf[q*4+1] = f2bf(av.y);
        abuf[q*4+2] = f2bf(av.z); abuf[q*4+3] = f2bf(av.w);
        wbuf[q*4+0] = f2bf(wv.x); wbuf[q*4+1] = f2bf(wv.y);
        wbuf[q*4+2] = f2bf(wv.z); wbuf[q*4+3] = f2bf(wv.w);
      }
      __syncthreads();
      *(uint4*)(As + sr * LDT + skh)     = *(uint4*)(abuf);
      *(uint4*)(As + sr * LDT + skh + 8) = *(uint4*)(abuf + 8);
      *(uint4*)(Ws + sr * LDT + skh)     = *(uint4*)(wbuf);
      *(uint4*)(Ws + sr * LDT + skh + 8) = *(uint4*)(wbuf + 8);
      __syncthreads();
    }
    bf16x8 af[4], bf[4];
#pragma unroll
    for (int mi = 0; mi < 4; mi++)
      af[mi] = *(const bf16x8*)(As + (wr * 64 + mi * 16 + lm) * LDT + lk8);
#pragma unroll
    for (int ni = 0; ni < 4; ni++)
      bf[ni] = *(const bf16x8*)(Ws + (wc * 64 + ni * 16 + lm) * LDT + lk8);
#pragma unroll
    for (int mi = 0; mi < 4; mi++)
#pragma unroll
      for (int ni = 0; ni < 4; ni++)
        acc[mi][ni] = __builtin_amdgcn_mfma_f32_16x16x32_bf16(
            af[mi], bf[ni], acc[mi][ni], 0, 0, 0);
  }
#pragma unroll
  for (int mi = 0; mi < 4; mi++) {
#pragma unroll
    for (int reg = 0; reg < 4; reg++) {
      const int row = row0 + wr * 64 + mi * 16 + (lane >> 4) * 4 + reg;
      if (row < M) {
        float* crow = C + (size_t)row * ldc;
#pragma unroll
        for (int ni = 0; ni < 4; ni++) {
          const int col = col0 + wc * 64 + ni * 16 + lm;
          crow[col] = acc[mi][ni][reg] + (bias ? bias[col] : 0.f);
        }
      }
    }
  }
}

__global__ __launch_bounds__(256) void gemm_mfma(
    const float* __restrict__ A, const float* __restrict__ W,
    const float* __restrict__ bias, float* __restrict__ C,
    int M, int N, int K, int ldc)
{
  mfma_gemm_body(A, W, bias, C, M, N, K, ldc);
}

__global__ __launch_bounds__(256) void gemm_mfma_dual(
    const float* __restrict__ A0, const float* __restrict__ W0,
    const float* __restrict__ b0, float* __restrict__ C0,
    const float* __restrict__ A1, const float* __restrict__ W1,
    const float* __restrict__ b1, float* __restrict__ C1,
    int M, int N, int K, int ldc)
{
  if (blockIdx.z == 0) mfma_gemm_body(A0, W0, b0, C0, M, N, K, ldc);
  else                 mfma_gemm_body(A1, W1, b1, C1, M, N, K, ldc);
}

__global__ __launch_bounds__(256) void transpose_x(
    const float* __restrict__ x, float* __restrict__ xt)
{
  const int i = blockIdx.x * 256 + threadIdx.x;
  if (i >= T_ * B_ * FEAT_) return;
  const int f = i % FEAT_;
  const int r = i / FEAT_;
  const int b = r % B_;
  const int t = r / B_;
  xt[i] = x[((long)b * T_ + t) * FEAT_ + f];
}

// ---------------- group-split persistent LSTM (R7 + sleepless spin) -------
__global__ __launch_bounds__(256, 1) void lstm_chunk(
    const float* __restrict__ gxF,   // [CH][B][4H] fwd x-gates (+bias)
    const float* __restrict__ gxB,   // [CH][B][4H] bwd (local t = CH-1-ls)
    float* __restrict__ hg0,         // [2][B][H] h for even steps
    float* __restrict__ hg1,         // [2][B][H] h for odd steps
    float* __restrict__ cg,          // [2][B][H] c carry
    float* __restrict__ outb,        // [T][B][2H]
    const float* __restrict__ WhhF, const float* __restrict__ WhhB,
    const int* __restrict__ lengths, int s0, int pbase,
    unsigned* __restrict__ bar)      // [16 groups] x 128B apart, monotonic
{
  __shared__ float h_l[2][576];      // 512 data + 64 pad (k + (k>>5)*4)
  __shared__ float gl[256];          // [row128][2b]
  __shared__ float c_l[64];
  __shared__ int   len_l[2];

  const int wg  = blockIdx.x;
  const int dir = wg >> 7;
  const int bp  = (wg >> 4) & 7;
  const int member = wg & 15;
  const int jbase = member * 32;
  const int gid = wg >> 4;           // 0..15
  const int tid = threadIdx.x;
  const int ks = tid & 15, rr = tid >> 4;

  if (tid < 2) len_l[tid] = lengths[bp * 2 + tid];
  if (tid < 64) {
    const int bl = tid >> 5, jj = tid & 31;
    c_l[tid] = cg[(dir * B_ + bp * 2 + bl) * H_ + jbase + jj];
  }

  // weights -> VGPRs: thread (rr,ks) owns rows rr*8..rr*8+7, k in [ks*32,+32)
  const float* Whh = dir ? WhhB : WhhF;
  float4 wreg[8][8];
#pragma unroll
  for (int q = 0; q < 8; q++) {
    const int row128 = rr * 8 + q;
    const int g = row128 >> 5, j = jbase + (row128 & 31);
    const float* wrow = Whh + (size_t)(g * 512 + j) * 512 + ks * 32;
#pragma unroll
    for (int i = 0; i < 8; i++)
      wreg[q][i] = *(const float4*)(wrow + i * 4);
  }
  __syncthreads();

  unsigned* bcnt = bar + gid * 32;   // 128B per group

  for (int ls = 0; ls < CH_; ls++) {
    const int s = s0 + ls;
    // prefetch this step's x-gates early (wave 0 only; consumed at pointwise)
    float gx0 = 0.f, gx1 = 0.f, gx2 = 0.f, gx3 = 0.f;
    if (tid < 64) {
      const int bl = tid >> 5, jj = tid & 31;
      const int b = bp * 2 + bl;
      const int lt = dir ? (CH_ - 1 - ls) : ls;
      const float* gx = (dir ? gxB : gxF) + ((size_t)lt * B_ + b) * H4_ + jbase + jj;
      gx0 = gx[0]; gx1 = gx[512]; gx2 = gx[1024]; gx3 = gx[1536];
    }
    // gather h (4KB): one coherent dwordx4 per thread
    {
      const float* hsrc = ((s & 1) ? hg1 : hg0) + (dir * B_ + bp * 2) * H_;
      const int base = (tid & 127) * 4;
      const int bl = tid >> 7;
      const f32x4 hv = coh_load_f4(hsrc + bl * H_ + base);
      *(f32x4*)&h_l[bl][base + (base >> 5) * 4] = hv;
    }
    __syncthreads();

    // dot: acc[q][bl], q = 8 rows, over k-slice [ks*32, +32)
    float acc[8][2];
#pragma unroll
    for (int q = 0; q < 8; q++) { acc[q][0] = 0.f; acc[q][1] = 0.f; }
#pragma unroll
    for (int i = 0; i < 8; i++) {
      const int kp = ks * 36 + i * 4;   // phys(ks*32 + i*4)
      const float4 h40 = *(const float4*)&h_l[0][kp];
      const float4 h41 = *(const float4*)&h_l[1][kp];
#pragma unroll
      for (int q = 0; q < 8; q++) {
        const float4 w4 = wreg[q][i];
        acc[q][0] = fmaf(w4.x, h40.x, acc[q][0]);
        acc[q][0] = fmaf(w4.y, h40.y, acc[q][0]);
        acc[q][0] = fmaf(w4.z, h40.z, acc[q][0]);
        acc[q][0] = fmaf(w4.w, h40.w, acc[q][0]);
        acc[q][1] = fmaf(w4.x, h41.x, acc[q][1]);
        acc[q][1] = fmaf(w4.y, h41.y, acc[q][1]);
        acc[q][1] = fmaf(w4.z, h41.z, acc[q][1]);
        acc[q][1] = fmaf(w4.w, h41.w, acc[q][1]);
      }
    }
    // reduce over ks (lane low 4 bits)
#pragma unroll
    for (int off = 1; off < 16; off <<= 1)
#pragma unroll
      for (int q = 0; q < 8; q++) {
        acc[q][0] += __shfl_xor(acc[q][0], off);
        acc[q][1] += __shfl_xor(acc[q][1], off);
      }
    if (ks == 0) {
#pragma unroll
      for (int q = 0; q < 8; q++) {
        gl[(rr * 8 + q) * 2 + 0] = acc[q][0];
        gl[(rr * 8 + q) * 2 + 1] = acc[q][1];
      }
    }
    __syncthreads();

    // pointwise (wave 0): 2 b x 32 j
    if (tid < 64) {
      const int bl = tid >> 5, jj = tid & 31;
      const int b = bp * 2 + bl;
      const int t = dir ? (T_ - 1 - s) : s;
      const float gi = gl[(0 * 32 + jj) * 2 + bl] + gx0;
      const float gf = gl[(1 * 32 + jj) * 2 + bl] + gx1;
      const float gc = gl[(2 * 32 + jj) * 2 + bl] + gx2;
      const float go = gl[(3 * 32 + jj) * 2 + bl] + gx3;
      const float iv = 1.f / (1.f + expf(-gi));
      const float fv = 1.f / (1.f + expf(-gf));
      const float gv = tanhf(gc);
      const float ov = 1.f / (1.f + expf(-go));
      const float c_old = c_l[tid];
      const int kb = jbase + jj;
      const float h_old = h_l[tid >> 5][kb + (kb >> 5) * 4];
      const float cn = fv * c_old + iv * gv;
      const float hn = ov * tanhf(cn);
      const bool mk = t < len_l[bl];
      c_l[tid] = mk ? cn : c_old;
      float* hdst = ((s & 1) ? hg0 : hg1) + (dir * B_ + b) * H_;
      coh_store_f32(&hdst[jbase + jj], mk ? hn : h_old);
      outb[((size_t)t * B_ + b) * H2_ + dir * H_ + jbase + jj] = mk ? hn : 0.f;

      if (ls != CH_ - 1 && tid == 0) {
        // all wave-0 h stores acked at coherence point, then arrive
        asm volatile("s_waitcnt vmcnt(0)" ::: "memory");
        __hip_atomic_fetch_add(bcnt, 1u, __ATOMIC_RELAXED,
                               __HIP_MEMORY_SCOPE_AGENT);
        const unsigned tgt = (unsigned)(pbase + ls + 1) * 16u;
        long tries = 0;
        // SLEEPLESS spin: 1 WG/CU -> this wave is alone on its SIMD,
        // spinning costs nothing; avoids s_sleep wakeup quantum.
        while (__hip_atomic_load(bcnt, __ATOMIC_RELAXED,
                                 __HIP_MEMORY_SCOPE_AGENT) < tgt) {
          if (++tries > (1L << 22)) break;  // fail loud, never hang
        }
      }
    }
    __syncthreads();
  }
  // carry c to next chunk (kernel boundary publishes)
  if (tid < 64) {
    const int bl = tid >> 5, jj = tid & 31;
    cg[(dir * B_ + bp * 2 + bl) * H_ + jbase + jj] = c_l[tid];
  }
}

// ---------------- decoder kernels (unchanged) ----------------
template <int ACT>
__global__ __launch_bounds__(256) void dotbn(
    const float* __restrict__ S1, const float* __restrict__ W1, int K1,
    const float* __restrict__ S2, const float* __restrict__ W2, int K2,
    const float* __restrict__ pre, int preStride,
    const float* __restrict__ bias,
    float* __restrict__ outp, int outStride, int N)
{
  const int idx = blockIdx.x * 256 + threadIdx.x;
  if (idx >= N * B_) return;
  const int b = idx & 15, n = idx >> 4;
  float acc = bias ? bias[n] : 0.f;
  if (pre) acc += pre[(long)b * preStride + n];
  {
    const float* s = S1 + (long)b * K1;
    const float* w = W1 + (long)n * K1;
#pragma unroll 4
    for (int k = 0; k < K1; k += 4) {
      float4 sv = *(const float4*)(s + k);
      float4 wv = *(const float4*)(w + k);
      acc = fmaf(sv.x, wv.x, acc); acc = fmaf(sv.y, wv.y, acc);
      acc = fmaf(sv.z, wv.z, acc); acc = fmaf(sv.w, wv.w, acc);
    }
  }
  if (S2) {
    const float* s = S2 + (long)b * K2;
    const float* w = W2 + (long)n * K2;
#pragma unroll 4
    for (int k = 0; k < K2; k += 4) {
      float4 sv = *(const float4*)(s + k);
      float4 wv = *(const float4*)(w + k);
      acc = fmaf(sv.x, wv.x, acc); acc = fmaf(sv.y, wv.y, acc);
      acc = fmaf(sv.z, wv.z, acc); acc = fmaf(sv.w, wv.w, acc);
    }
  }
  if (ACT == 1) acc = tanhf(acc);
  outp[(long)b * outStride + n] = acc;
}

__global__ __launch_bounds__(256) void dec_conv(
    const float* __restrict__ alpha, const float* __restrict__ cw,
    float* __restrict__ conv)
{
  const int idx = blockIdx.x * 256 + threadIdx.x;
  if (idx >= B_ * 10 * T_) return;
  const int t = idx % T_;
  const int f = (idx / T_) % 10;
  const int b = idx / (10 * T_);
  const float* a = alpha + b * T_;
  const float* w = cw + f * 100;
  float acc = 0.f;
  const int k0 = (50 - t) > 0 ? (50 - t) : 0;
  const int k1 = (T_ + 50 - t) < 100 ? (T_ + 50 - t) : 100;
  for (int k = k0; k < k1; k++) acc = fmaf(a[t + k - 50], w[k], acc);
  conv[idx] = acc;
}

__global__ __launch_bounds__(256) void att_e(
    const float* __restrict__ se, const float* __restrict__ he,
    const float* __restrict__ conv, const float* __restrict__ W_fe,
    const float* __restrict__ W_ee, float* __restrict__ e)
{
  __shared__ float wfe[10240];
  __shared__ float ses[1024];
  __shared__ float wee[1024];
  __shared__ float red[4];
  const int wg = blockIdx.x;
  const int b = wg / 50, t0 = (wg % 50) * 16;
  const int tid = threadIdx.x;
  for (int i = tid; i < 10240; i += 256) wfe[i] = W_fe[i];
  for (int i = tid; i < 1024; i += 256) {
    ses[i] = se[b * H2_ + i];
    wee[i] = W_ee[i];
  }
  __syncthreads();
  for (int tt = 0; tt < 16; tt++) {
    const int t = t0 + tt;
    float cv[10];
#pragma unroll
    for (int f = 0; f < 10; f++) cv[f] = conv[(b * 10 + f) * T_ + t];
    const float* hrow = he + ((long)t * B_ + b) * H2_;
    float part = 0.f;
#pragma unroll
    for (int q = 0; q < 4; q++) {
      const int d = tid + q * 256;
      float loc = 0.f;
      const float* wf = &wfe[d * 10];
#pragma unroll
      for (int f = 0; f < 10; f++) loc = fmaf(cv[f], wf[f], loc);
      const float val = tanhf(ses[d] + hrow[d] + loc);
      part = fmaf(val, wee[d], part);
    }
#pragma unroll
    for (int off = 32; off; off >>= 1) part += __shfl_down(part, off);
    if ((tid & 63) == 0) red[tid >> 6] = part;
    __syncthreads();
    if (tid == 0) e[b * T_ + t] = red[0] + red[1] + red[2] + red[3];
    __syncthreads();
  }
}

__global__ __launch_bounds__(256) void att_softmax(
    const float* __restrict__ e, const int* __restrict__ lengths,
    float* __restrict__ alpha)
{
  __shared__ float red[4];
  __shared__ float bc, bc2;
  const int b = blockIdx.x, tid = threadIdx.x;
  const int len = lengths[b];
  float v[4];
  float mx = -1e30f;
#pragma unroll
  for (int q = 0; q < 4; q++) {
    const int t = tid + q * 256;
    v[q] = (t < T_) ? e[b * T_ + t] : -1e30f;
    mx = fmaxf(mx, v[q]);
  }
#pragma unroll
  for (int off = 32; off; off >>= 1) mx = fmaxf(mx, __shfl_down(mx, off));
  if ((tid & 63) == 0) red[tid >> 6] = mx;
  __syncthreads();
  if (tid == 0) bc = fmaxf(fmaxf(red[0], red[1]), fmaxf(red[2], red[3]));
  __syncthreads();
  const float m = bc;
  float ex[4];
  float s = 0.f;
#pragma unroll
  for (int q = 0; q < 4; q++) {
    const int t = tid + q * 256;
    ex[q] = (t < T_ && t < len) ? expf(v[q] - m) : 0.f;
    s += ex[q];
  }
#pragma unroll
  for (int off = 32; off; off >>= 1) s += __shfl_down(s, off);
  __syncthreads();
  if ((tid & 63) == 0) red[tid >> 6] = s;
  __syncthreads();
  if (tid == 0) bc2 = red[0] + red[1] + red[2] + red[3];
  __syncthreads();
  const float inv = 1.f / bc2;
#pragma unroll
  for (int q = 0; q < 4; q++) {
    const int t = tid + q * 256;
    if (t < T_) alpha[b * T_ + t] = ex[q] * inv;
  }
}

__global__ __launch_bounds__(256) void att_g(
    const float* __restrict__ alpha, const float* __restrict__ hb,
    float* __restrict__ g)
{
  const int idx = blockIdx.x * 256 + threadIdx.x;
  const int d = idx & (H2_ - 1), b = idx >> 10;
  const float* ab = alpha + b * T_;
  float acc = 0.f;
#pragma unroll 8
  for (int t = 0; t < T_; t++)
    acc = fmaf(ab[t], hb[((long)t * B_ + b) * H2_ + d], acc);
  g[idx] = acc;
}

__global__ __launch_bounds__(256) void dec_update(
    const float* __restrict__ rec, float* __restrict__ s, float* __restrict__ c)
{
  const int idx = blockIdx.x * 256 + threadIdx.x;
  if (idx >= B_ * H_) return;
  const int jj = idx & 511, b = idx >> 9;
  const float* r = rec + b * H4_;
  const float gi = r[jj], gf = r[jj + 512], gc = r[jj + 1024], go = r[jj + 1536];
  const float iv = tanhf(gi * 0.5f) * 0.5f + 0.5f;
  const float fv = tanhf(gf * 0.5f) * 0.5f + 0.5f;
  const float cg = tanhf(gc);
  const float ov = tanhf(go * 0.5f) * 0.5f + 0.5f;
  const float cn = fv * c[idx] + iv * cg;
  const float sn = ov * tanhf(cn);
  c[idx] = cn;
  s[idx] = sn;
}

extern "C" void kernel_launch(void* const* d_in, const int* in_sizes, int n_in,
                              void* d_out, int out_size, void* d_ws, size_t ws_size,
                              hipStream_t stream)
{
  const float* x       = (const float*)d_in[0];
  const int*   lengths = (const int*)  d_in[1];
  const float* target  = (const float*)d_in[2];
  const float* Wih0    = (const float*)d_in[3];
  const float* Whh0    = (const float*)d_in[4];
  const float* b0      = (const float*)d_in[5];
  const float* WihL    = (const float*)d_in[6];
  const float* WhhL    = (const float*)d_in[7];
  const float* bL      = (const float*)d_in[8];
  const float* W_se    = (const float*)d_in[9];
  const float* W_he    = (const float*)d_in[10];
  const float* b_he    = (const float*)d_in[11];
  const float* W_ee    = (const float*)d_in[12];
  const float* conv_w  = (const float*)d_in[13];
  const float* W_fe    = (const float*)d_in[14];
  const float* W_sy    = (const float*)d_in[15];
  const float* W_gy    = (const float*)d_in[16];
  const float* b_gy    = (const float*)d_in[17];
  const float* W_yy    = (const float*)d_in[18];
  const float* b_yy    = (const float*)d_in[19];
  const float* W_ys    = (const float*)d_in[20];
  const float* W_ss    = (const float*)d_in[21];
  const float* W_gs    = (const float*)d_in[22];
  const float* b_gs    = (const float*)d_in[23];
  float* out = (float*)d_out;

  // ---- workspace layout (~119.3 MB) ----
  float* bufA = (float*)d_ws;
  float* bufB = bufA + (size_t)T_ * B_ * H2_;
  float* gxc  = bufB + (size_t)T_ * B_ * H2_;
  float* gxcF = gxc;
  float* gxcB = gxc + (size_t)CH_ * B_ * H4_;
  float* he   = bufB;
  float* ysp  = gxc;
  float* st   = gxc + (size_t)2 * CH_ * B_ * H4_;
  float* hg0  = st;
  float* hg1  = hg0 + 2 * B_ * H_;
  float* cg   = hg1 + 2 * B_ * H_;
  float* sdec = cg + 2 * B_ * H_;
  float* cdec = sdec + B_ * H_;
  float* alpha= cdec + B_ * H_;
  float* conv = alpha + B_ * T_;
  float* ebuf = conv + B_ * 10 * T_;
  float* sebuf= ebuf + B_ * T_;
  float* gvec = sebuf + B_ * H2_;
  float* zvec = gvec + B_ * H2_;
  float* rec  = zvec + B_ * H_;
  unsigned* bar = (unsigned*)(rec + B_ * H4_ + 32);  // 16 groups x 128B

  (void)hipMemsetAsync(bar, 0, 2048, stream);  // once; monotonic thereafter

  // ---- encoder ----
  transpose_x<<<(T_ * B_ * FEAT_ + 255) / 256, 256, 0, stream>>>(x, bufA);

  float* inb  = bufA;
  float* outb = bufB;
  for (int l = 0; l < 4; l++) {
    const int Kin = (l == 0) ? FEAT_ : H2_;
    const float *WihF, *WihB, *WhhF, *WhhB, *bF, *bB;
    if (l == 0) {
      WihF = Wih0;                 WihB = Wih0 + (size_t)H4_ * FEAT_;
      WhhF = Whh0;                 WhhB = Whh0 + (size_t)H4_ * H_;
      bF = b0;                     bB = b0 + H4_;
    } else {
      const size_t o = (size_t)(l - 1) * 2;
      WihF = WihL + o * H4_ * H2_; WihB = WihF + (size_t)H4_ * H2_;
      WhhF = WhhL + o * H4_ * H_;  WhhB = WhhF + (size_t)H4_ * H_;
      bF = bL + o * H4_;           bB = bF + H4_;
    }
    (void)hipMemsetAsync(hg0, 0, (size_t)3 * 2 * B_ * H_ * sizeof(float), stream);
    dim3 gg(H4_ / GBN, (CH_ * B_ + GBM - 1) / GBM, 2);  // (16, 7, 2)
    for (int c = 0; c < T_ / CH_; c++) {
      const int s0 = c * CH_;
      gemm_mfma_dual<<<gg, 256, 0, stream>>>(
          inb + (size_t)s0 * B_ * Kin, WihF, bF, gxcF,
          inb + (size_t)(T_ - s0 - CH_) * B_ * Kin, WihB, bB, gxcB,
          CH_ * B_, H4_, Kin, H4_);
      const int pbase = (l * (T_ / CH_) + c) * (CH_ - 1);
      lstm_chunk<<<256, 256, 0, stream>>>(gxcF, gxcB, hg0, hg1, cg, outb,
                                          WhhF, WhhB, lengths, s0, pbase, bar);
    }
    float* tmp = inb; inb = outb; outb = tmp;
  }
  float* hb = inb;  // final encoder output = bufA

  // ---- decoder precompute (bf16 MFMA) ----
  {
    dim3 ghe(H2_ / GBN, (T_ * B_) / GBM);
    gemm_mfma<<<ghe, 256, 0, stream>>>(hb, W_he, b_he, he, T_ * B_, H2_, H2_, H2_);
    dim3 gys(H4_ / GBN, (B_ * NL_ + GBM - 1) / GBM);
    gemm_mfma<<<gys, 256, 0, stream>>>(target, W_ys, b_gs, ysp, B_ * NL_, H4_, CC_, H4_);
  }
  (void)hipMemsetAsync(sdec, 0, (size_t)(2 * B_ * H_ + B_ * T_) * sizeof(float), stream);

  // ---- decoder steps ----
  for (int step = 0; step < NL_; step++) {
    dec_conv<<<(B_ * 10 * T_ + 255) / 256, 256, 0, stream>>>(alpha, conv_w, conv);
    dotbn<0><<<(B_ * H2_) / 256, 256, 0, stream>>>(
        sdec, W_se, H_, nullptr, nullptr, 0, nullptr, 0, nullptr, sebuf, H2_, H2_);
    att_e<<<800, 256, 0, stream>>>(sebuf, he, conv, W_fe, W_ee, ebuf);
    att_softmax<<<B_, 256, 0, stream>>>(ebuf, lengths, alpha);
    att_g<<<(B_ * H2_) / 256, 256, 0, stream>>>(alpha, hb, gvec);
    dotbn<1><<<(B_ * H_) / 256, 256, 0, stream>>>(
        gvec, W_gy, H2_, sdec, W_sy, H_, nullptr, 0, b_gy, zvec, H_, H_);
    dotbn<0><<<(B_ * CC_ + 255) / 256, 256, 0, stream>>>(
        zvec, W_yy, H_, nullptr, nullptr, 0, nullptr, 0, b_yy,
        out + (size_t)step * CC_, NL_ * CC_, CC_);
    dotbn<0><<<(B_ * H4_) / 256, 256, 0, stream>>>(
        sdec, W_ss, H_, gvec, W_gs, H2_, ysp + (size_t)step * H4_, NL_ * H4_,
        nullptr, rec, H4_, H4_);
    dec_update<<<(B_ * H_) / 256, 256, 0, stream>>>(rec, sdec, cdec);
  }
}

// Round 11
// 56978.363 us; speedup vs baseline: 1.0838x; 1.0838x over previous
//
#include <hip/hip_runtime.h>
#include <math.h>

// Round 11: compact-MFMA encoder. 32 WGs (16/dir), each owns 128 gate-rows
// for ALL batches. Dot = bf16 hi/lo split MFMA (fp32-grade). Tests the
// DPM-downclock hypothesis (256 latency-idle CUs -> low clocks) by
// concentrating the recurrence on 32 CUs. Barrier = R10 relaxed monotonic.
// Decoder + GEMMs unchanged.

#define T_    800
#define B_    16
#define FEAT_ 120
#define H_    512
#define H2_   1024
#define H4_   2048
#define CC_   5000
#define NL_   100
#define CH_   50
#define HPAD  536

typedef __attribute__((ext_vector_type(8))) short bf16x8;
typedef __attribute__((ext_vector_type(4))) float f32x4;

__device__ __forceinline__ void coh_store_f32(float* p, float v) {
  asm volatile("global_store_dword %0, %1, off sc0 sc1"
               :: "v"(p), "v"(v) : "memory");
}
__device__ __forceinline__ void coh_load8_f4(
    const float* p0, const float* p1, const float* p2, const float* p3,
    const float* p4, const float* p5, const float* p6, const float* p7,
    f32x4* o)
{
  asm volatile(
      "global_load_dwordx4 %0, %8, off sc0 sc1\n\t"
      "global_load_dwordx4 %1, %9, off sc0 sc1\n\t"
      "global_load_dwordx4 %2, %10, off sc0 sc1\n\t"
      "global_load_dwordx4 %3, %11, off sc0 sc1\n\t"
      "global_load_dwordx4 %4, %12, off sc0 sc1\n\t"
      "global_load_dwordx4 %5, %13, off sc0 sc1\n\t"
      "global_load_dwordx4 %6, %14, off sc0 sc1\n\t"
      "global_load_dwordx4 %7, %15, off sc0 sc1\n\t"
      "s_waitcnt vmcnt(0)"
      : "=&v"(o[0]), "=&v"(o[1]), "=&v"(o[2]), "=&v"(o[3]),
        "=&v"(o[4]), "=&v"(o[5]), "=&v"(o[6]), "=&v"(o[7])
      : "v"(p0), "v"(p1), "v"(p2), "v"(p3), "v"(p4), "v"(p5), "v"(p6), "v"(p7)
      : "memory");
}

__device__ __forceinline__ unsigned short f2bf(float f) {
  unsigned u = __builtin_bit_cast(unsigned, f);
  u += 0x7FFFu + ((u >> 16) & 1u);
  return (unsigned short)(u >> 16);
}
__device__ __forceinline__ float bf2f(unsigned short s) {
  return __builtin_bit_cast(float, (unsigned)s << 16);
}

// ---------------- bf16 MFMA GEMM (unchanged, validated) ----------------
#define GBM 128
#define GBN 128
#define GBK 32
#define LDT 40

__device__ __forceinline__ void mfma_gemm_body(
    const float* __restrict__ A, const float* __restrict__ W,
    const float* __restrict__ bias, float* __restrict__ C,
    int M, int N, int K, int ldc)
{
  __shared__ unsigned short As[GBM * LDT];
  __shared__ unsigned short Ws[GBN * LDT];
  const int tid = threadIdx.x;
  const int row0 = blockIdx.y * GBM, col0 = blockIdx.x * GBN;
  const int lane = tid & 63, w = tid >> 6;
  const int wr = w >> 1, wc = w & 1;
  const int lm = lane & 15, lk8 = (lane >> 4) * 8;

  f32x4 acc[4][4];
#pragma unroll
  for (int i = 0; i < 4; i++)
#pragma unroll
    for (int j = 0; j < 4; j++) acc[i][j] = (f32x4)(0.f);

  const int sr = tid >> 1, skh = (tid & 1) * 16;

  for (int kt = 0; kt < K; kt += GBK) {
    {
      const int ar = row0 + sr;
      const int wrow = col0 + sr;
      unsigned short abuf[16], wbuf[16];
#pragma unroll
      for (int q = 0; q < 4; q++) {
        const int k0 = kt + skh + q * 4;
        float4 av = make_float4(0.f, 0.f, 0.f, 0.f);
        float4 wv = make_float4(0.f, 0.f, 0.f, 0.f);
        if (k0 + 4 <= K) {
          if (ar < M)   av = *(const float4*)(A + (size_t)ar * K + k0);
          if (wrow < N) wv = *(const float4*)(W + (size_t)wrow * K + k0);
        }
        abuf[q*4+0] = f2bf(av.x); abuf[q*4+1] = f2bf(av.y);
        abuf[q*4+2] = f2bf(av.z); abuf[q*4+3] = f2bf(av.w);
        wbuf[q*4+0] = f2bf(wv.x); wbuf[q*4+1] = f2bf(wv.y);
        wbuf[q*4+2] = f2bf(wv.z); wbuf[q*4+3] = f2bf(wv.w);
      }
      __syncthreads();
      *(uint4*)(As + sr * LDT + skh)     = *(uint4*)(abuf);
      *(uint4*)(As + sr * LDT + skh + 8) = *(uint4*)(abuf + 8);
      *(uint4*)(Ws + sr * LDT + skh)     = *(uint4*)(wbuf);
      *(uint4*)(Ws + sr * LDT + skh + 8) = *(uint4*)(wbuf + 8);
      __syncthreads();
    }
    bf16x8 af[4], bf[4];
#pragma unroll
    for (int mi = 0; mi < 4; mi++)
      af[mi] = *(const bf16x8*)(As + (wr * 64 + mi * 16 + lm) * LDT + lk8);
#pragma unroll
    for (int ni = 0; ni < 4; ni++)
      bf[ni] = *(const bf16x8*)(Ws + (wc * 64 + ni * 16 + lm) * LDT + lk8);
#pragma unroll
    for (int mi = 0; mi < 4; mi++)
#pragma unroll
      for (int ni = 0; ni < 4; ni++)
        acc[mi][ni] = __builtin_amdgcn_mfma_f32_16x16x32_bf16(
            af[mi], bf[ni], acc[mi][ni], 0, 0, 0);
  }
#pragma unroll
  for (int mi = 0; mi < 4; mi++) {
#pragma unroll
    for (int reg = 0; reg < 4; reg++) {
      const int row = row0 + wr * 64 + mi * 16 + (lane >> 4) * 4 + reg;
      if (row < M) {
        float* crow = C + (size_t)row * ldc;
#pragma unroll
        for (int ni = 0; ni < 4; ni++) {
          const int col = col0 + wc * 64 + ni * 16 + lm;
          crow[col] = acc[mi][ni][reg] + (bias ? bias[col] : 0.f);
        }
      }
    }
  }
}

__global__ __launch_bounds__(256) void gemm_mfma(
    const float* __restrict__ A, const float* __restrict__ W,
    const float* __restrict__ bias, float* __restrict__ C,
    int M, int N, int K, int ldc)
{
  mfma_gemm_body(A, W, bias, C, M, N, K, ldc);
}

__global__ __launch_bounds__(256) void gemm_mfma_dual(
    const float* __restrict__ A0, const float* __restrict__ W0,
    const float* __restrict__ b0, float* __restrict__ C0,
    const float* __restrict__ A1, const float* __restrict__ W1,
    const float* __restrict__ b1, float* __restrict__ C1,
    int M, int N, int K, int ldc)
{
  if (blockIdx.z == 0) mfma_gemm_body(A0, W0, b0, C0, M, N, K, ldc);
  else                 mfma_gemm_body(A1, W1, b1, C1, M, N, K, ldc);
}

__global__ __launch_bounds__(256) void transpose_x(
    const float* __restrict__ x, float* __restrict__ xt)
{
  const int i = blockIdx.x * 256 + threadIdx.x;
  if (i >= T_ * B_ * FEAT_) return;
  const int f = i % FEAT_;
  const int r = i / FEAT_;
  const int b = r % B_;
  const int t = r / B_;
  xt[i] = x[((long)b * T_ + t) * FEAT_ + f];
}

// ---------------- compact-MFMA persistent LSTM ----------------
// grid = 32 WGs: dir = wg>>4, member m = wg&15 owns j in [m*32,+32) for ALL b.
// Row order within WG: row128 = gate*32 + jj. Weights hi/lo bf16 in VGPRs.
__global__ __launch_bounds__(256, 1) void lstm_compact(
    const float* __restrict__ gxF,   // [CH][B][4H]
    const float* __restrict__ gxB,
    float* __restrict__ hg0,         // [2][B][H] even-step h
    float* __restrict__ hg1,         // [2][B][H] odd-step h
    float* __restrict__ cg,          // [2][B][H]
    float* __restrict__ outb,        // [T][B][2H]
    const float* __restrict__ WhhF, const float* __restrict__ WhhB,
    const int* __restrict__ lengths, int s0, int pbase,
    unsigned* __restrict__ bar)
{
  __shared__ unsigned short h_hi[16][HPAD];
  __shared__ unsigned short h_lo[16][HPAD];
  __shared__ float gl[128 * 16];     // [row128][b]
  __shared__ float c_l[512];         // [jj*16 + b]
  __shared__ int   len_l[16];

  const int wg  = blockIdx.x;
  const int dir = wg >> 4;
  const int m   = wg & 15;
  const int tid = threadIdx.x;
  const int lane = tid & 63, w = tid >> 6;
  const int lrow = lane & 15, lko = (lane >> 4) * 8;

  if (tid < 16) len_l[tid] = lengths[tid];
  {
    const int eA = tid, eB = tid + 256;
    c_l[eA] = cg[(dir * 16 + (eA & 15)) * 512 + m * 32 + (eA >> 4)];
    c_l[eB] = cg[(dir * 16 + (eB & 15)) * 512 + m * 32 + (eB >> 4)];
  }

  // ---- weights -> VGPRs as hi/lo bf16 (fragment layout: row=lane&15,
  //      k-off=(lane>>4)*8; validated by the gemm kernel) ----
  const float* Whh = dir ? WhhB : WhhF;
  bf16x8 whi[2][16], wlo[2][16];
#pragma unroll
  for (int rt = 0; rt < 2; rt++) {
    const int row128 = (w * 2 + rt) * 16 + lrow;
    const int g = row128 >> 5, jj = row128 & 31;
    const float* wr = Whh + (size_t)(g * 512 + m * 32 + jj) * 512 + lko;
#pragma unroll
    for (int kt = 0; kt < 16; kt++) {
      unsigned short h8[8], l8[8];
#pragma unroll
      for (int i = 0; i < 8; i++) {
        const float v = wr[kt * 32 + i];
        h8[i] = f2bf(v);
        l8[i] = f2bf(v - bf2f(h8[i]));
      }
      whi[rt][kt] = *(bf16x8*)h8;
      wlo[rt][kt] = *(bf16x8*)l8;
    }
  }
  __syncthreads();

  unsigned* bcnt = bar + dir * 32;   // 128B apart

  const int b0  = tid & 15;          // pointwise batch
  const int jjA = tid >> 4;          // 0..15
  const int jjB = jjA + 16;          // 16..31
  const int gb_ = tid >> 4;          // gather batch
  const int gk0 = (tid & 15) * 32;   // gather k-base

  for (int ls = 0; ls < CH_; ls++) {
    const int s = s0 + ls;
    const int lt = dir ? (CH_ - 1 - ls) : ls;
    // gx prefetch (8 values/thread)
    const float* gxp = (dir ? gxB : gxF) + ((size_t)lt * 16 + b0) * 2048 + m * 32;
    float ga[4], gb[4];
#pragma unroll
    for (int g = 0; g < 4; g++) { ga[g] = gxp[g * 512 + jjA]; gb[g] = gxp[g * 512 + jjB]; }

    // ---- obtain h(s): gather fp32, split hi/lo into LDS ----
    if (s == 0) {
      const uint4 z = make_uint4(0, 0, 0, 0);
#pragma unroll
      for (int o = 0; o < 4; o++) {
        *(uint4*)&h_hi[gb_][gk0 + o * 8] = z;
        *(uint4*)&h_lo[gb_][gk0 + o * 8] = z;
      }
    } else {
      const float* hsrc = ((s & 1) ? hg1 : hg0) + (dir * 16 + gb_) * 512 + gk0;
      f32x4 hv[8];
      coh_load8_f4(hsrc, hsrc + 4, hsrc + 8, hsrc + 12,
                   hsrc + 16, hsrc + 20, hsrc + 24, hsrc + 28, hv);
      unsigned short sh[32], sl[32];
#pragma unroll
      for (int q = 0; q < 8; q++)
#pragma unroll
        for (int i = 0; i < 4; i++) {
          const float v = hv[q][i];
          const unsigned short hh = f2bf(v);
          sh[q * 4 + i] = hh;
          sl[q * 4 + i] = f2bf(v - bf2f(hh));
        }
#pragma unroll
      for (int o = 0; o < 4; o++) {
        *(uint4*)&h_hi[gb_][gk0 + o * 8] = *(uint4*)(sh + o * 8);
        *(uint4*)&h_lo[gb_][gk0 + o * 8] = *(uint4*)(sl + o * 8);
      }
    }
    __syncthreads();

    // ---- MFMA dot: acc[rt] = Whh_rows x h  (hi*hi + lo*hi + hi*lo) ----
    f32x4 acc[2];
    acc[0] = (f32x4)(0.f); acc[1] = (f32x4)(0.f);
#pragma unroll
    for (int kt = 0; kt < 16; kt++) {
      const bf16x8 bh = *(const bf16x8*)&h_hi[lrow][kt * 32 + lko];
      const bf16x8 bl = *(const bf16x8*)&h_lo[lrow][kt * 32 + lko];
#pragma unroll
      for (int rt = 0; rt < 2; rt++) {
        acc[rt] = __builtin_amdgcn_mfma_f32_16x16x32_bf16(whi[rt][kt], bh, acc[rt], 0, 0, 0);
        acc[rt] = __builtin_amdgcn_mfma_f32_16x16x32_bf16(wlo[rt][kt], bh, acc[rt], 0, 0, 0);
        acc[rt] = __builtin_amdgcn_mfma_f32_16x16x32_bf16(whi[rt][kt], bl, acc[rt], 0, 0, 0);
      }
    }
#pragma unroll
    for (int rt = 0; rt < 2; rt++) {
      const int rbase = (w * 2 + rt) * 16 + (lane >> 4) * 4;
#pragma unroll
      for (int r = 0; r < 4; r++)
        gl[(rbase + r) * 16 + lrow] = acc[rt][r];
    }
    __syncthreads();

    // ---- pointwise: 2 elements per thread (jjA, jjB; same b0) ----
    const int t = dir ? (T_ - 1 - s) : s;
    const bool mk = t < len_l[b0];
    float houtA, houtB, hnA, hnB;
    {
      const float gi = gl[(0 * 32 + jjA) * 16 + b0] + ga[0];
      const float gf = gl[(1 * 32 + jjA) * 16 + b0] + ga[1];
      const float gc = gl[(2 * 32 + jjA) * 16 + b0] + ga[2];
      const float go = gl[(3 * 32 + jjA) * 16 + b0] + ga[3];
      const float iv = 1.f / (1.f + expf(-gi));
      const float fv = 1.f / (1.f + expf(-gf));
      const float gv = tanhf(gc);
      const float ov = 1.f / (1.f + expf(-go));
      const float c_old = c_l[tid];
      const float h_old = bf2f(h_hi[b0][m * 32 + jjA]) + bf2f(h_lo[b0][m * 32 + jjA]);
      const float cn = fv * c_old + iv * gv;
      hnA = ov * tanhf(cn);
      c_l[tid] = mk ? cn : c_old;
      houtA = mk ? hnA : h_old;
    }
    {
      const float gi = gl[(0 * 32 + jjB) * 16 + b0] + gb[0];
      const float gf = gl[(1 * 32 + jjB) * 16 + b0] + gb[1];
      const float gc = gl[(2 * 32 + jjB) * 16 + b0] + gb[2];
      const float go = gl[(3 * 32 + jjB) * 16 + b0] + gb[3];
      const float iv = 1.f / (1.f + expf(-gi));
      const float fv = 1.f / (1.f + expf(-gf));
      const float gv = tanhf(gc);
      const float ov = 1.f / (1.f + expf(-go));
      const float c_old = c_l[tid + 256];
      const float h_old = bf2f(h_hi[b0][m * 32 + jjB]) + bf2f(h_lo[b0][m * 32 + jjB]);
      const float cn = fv * c_old + iv * gv;
      hnB = ov * tanhf(cn);
      c_l[tid + 256] = mk ? cn : c_old;
      houtB = mk ? hnB : h_old;
    }
    // publish h (sc) — on the chain; outb deferred past the barrier
    {
      float* hdst = ((s & 1) ? hg0 : hg1) + (dir * 16 + b0) * 512 + m * 32;
      coh_store_f32(&hdst[jjA], houtA);
      coh_store_f32(&hdst[jjB], houtB);
    }
    asm volatile("s_waitcnt vmcnt(0)" ::: "memory");  // per-wave drain
    __syncthreads();                                   // all waves drained
    if (ls != CH_ - 1 && tid == 0) {
      __hip_atomic_fetch_add(bcnt, 1u, __ATOMIC_RELAXED, __HIP_MEMORY_SCOPE_AGENT);
      const unsigned tgt = (unsigned)(pbase + ls + 1) * 16u;
      long tries = 0;
      while (__hip_atomic_load(bcnt, __ATOMIC_RELAXED,
                               __HIP_MEMORY_SCOPE_AGENT) < tgt) {
        if (++tries > (1L << 22)) break;  // fail loud, never hang
      }
    }
    __syncthreads();
    // outb off-chain
    outb[((size_t)t * 16 + b0) * H2_ + dir * 512 + m * 32 + jjA] = mk ? hnA : 0.f;
    outb[((size_t)t * 16 + b0) * H2_ + dir * 512 + m * 32 + jjB] = mk ? hnB : 0.f;
  }
  // carry c
  {
    const int eA = tid, eB = tid + 256;
    cg[(dir * 16 + (eA & 15)) * 512 + m * 32 + (eA >> 4)] = c_l[eA];
    cg[(dir * 16 + (eB & 15)) * 512 + m * 32 + (eB >> 4)] = c_l[eB];
  }
}

// ---------------- decoder kernels (unchanged) ----------------
template <int ACT>
__global__ __launch_bounds__(256) void dotbn(
    const float* __restrict__ S1, const float* __restrict__ W1, int K1,
    const float* __restrict__ S2, const float* __restrict__ W2, int K2,
    const float* __restrict__ pre, int preStride,
    const float* __restrict__ bias,
    float* __restrict__ outp, int outStride, int N)
{
  const int idx = blockIdx.x * 256 + threadIdx.x;
  if (idx >= N * B_) return;
  const int b = idx & 15, n = idx >> 4;
  float acc = bias ? bias[n] : 0.f;
  if (pre) acc += pre[(long)b * preStride + n];
  {
    const float* s = S1 + (long)b * K1;
    const float* w = W1 + (long)n * K1;
#pragma unroll 4
    for (int k = 0; k < K1; k += 4) {
      float4 sv = *(const float4*)(s + k);
      float4 wv = *(const float4*)(w + k);
      acc = fmaf(sv.x, wv.x, acc); acc = fmaf(sv.y, wv.y, acc);
      acc = fmaf(sv.z, wv.z, acc); acc = fmaf(sv.w, wv.w, acc);
    }
  }
  if (S2) {
    const float* s = S2 + (long)b * K2;
    const float* w = W2 + (long)n * K2;
#pragma unroll 4
    for (int k = 0; k < K2; k += 4) {
      float4 sv = *(const float4*)(s + k);
      float4 wv = *(const float4*)(w + k);
      acc = fmaf(sv.x, wv.x, acc); acc = fmaf(sv.y, wv.y, acc);
      acc = fmaf(sv.z, wv.z, acc); acc = fmaf(sv.w, wv.w, acc);
    }
  }
  if (ACT == 1) acc = tanhf(acc);
  outp[(long)b * outStride + n] = acc;
}

__global__ __launch_bounds__(256) void dec_conv(
    const float* __restrict__ alpha, const float* __restrict__ cw,
    float* __restrict__ conv)
{
  const int idx = blockIdx.x * 256 + threadIdx.x;
  if (idx >= B_ * 10 * T_) return;
  const int t = idx % T_;
  const int f = (idx / T_) % 10;
  const int b = idx / (10 * T_);
  const float* a = alpha + b * T_;
  const float* w = cw + f * 100;
  float acc = 0.f;
  const int k0 = (50 - t) > 0 ? (50 - t) : 0;
  const int k1 = (T_ + 50 - t) < 100 ? (T_ + 50 - t) : 100;
  for (int k = k0; k < k1; k++) acc = fmaf(a[t + k - 50], w[k], acc);
  conv[idx] = acc;
}

__global__ __launch_bounds__(256) void att_e(
    const float* __restrict__ se, const float* __restrict__ he,
    const float* __restrict__ conv, const float* __restrict__ W_fe,
    const float* __restrict__ W_ee, float* __restrict__ e)
{
  __shared__ float wfe[10240];
  __shared__ float ses[1024];
  __shared__ float wee[1024];
  __shared__ float red[4];
  const int wg = blockIdx.x;
  const int b = wg / 50, t0 = (wg % 50) * 16;
  const int tid = threadIdx.x;
  for (int i = tid; i < 10240; i += 256) wfe[i] = W_fe[i];
  for (int i = tid; i < 1024; i += 256) {
    ses[i] = se[b * H2_ + i];
    wee[i] = W_ee[i];
  }
  __syncthreads();
  for (int tt = 0; tt < 16; tt++) {
    const int t = t0 + tt;
    float cv[10];
#pragma unroll
    for (int f = 0; f < 10; f++) cv[f] = conv[(b * 10 + f) * T_ + t];
    const float* hrow = he + ((long)t * B_ + b) * H2_;
    float part = 0.f;
#pragma unroll
    for (int q = 0; q < 4; q++) {
      const int d = tid + q * 256;
      float loc = 0.f;
      const float* wf = &wfe[d * 10];
#pragma unroll
      for (int f = 0; f < 10; f++) loc = fmaf(cv[f], wf[f], loc);
      const float val = tanhf(ses[d] + hrow[d] + loc);
      part = fmaf(val, wee[d], part);
    }
#pragma unroll
    for (int off = 32; off; off >>= 1) part += __shfl_down(part, off);
    if ((tid & 63) == 0) red[tid >> 6] = part;
    __syncthreads();
    if (tid == 0) e[b * T_ + t] = red[0] + red[1] + red[2] + red[3];
    __syncthreads();
  }
}

__global__ __launch_bounds__(256) void att_softmax(
    const float* __restrict__ e, const int* __restrict__ lengths,
    float* __restrict__ alpha)
{
  __shared__ float red[4];
  __shared__ float bc, bc2;
  const int b = blockIdx.x, tid = threadIdx.x;
  const int len = lengths[b];
  float v[4];
  float mx = -1e30f;
#pragma unroll
  for (int q = 0; q < 4; q++) {
    const int t = tid + q * 256;
    v[q] = (t < T_) ? e[b * T_ + t] : -1e30f;
    mx = fmaxf(mx, v[q]);
  }
#pragma unroll
  for (int off = 32; off; off >>= 1) mx = fmaxf(mx, __shfl_down(mx, off));
  if ((tid & 63) == 0) red[tid >> 6] = mx;
  __syncthreads();
  if (tid == 0) bc = fmaxf(fmaxf(red[0], red[1]), fmaxf(red[2], red[3]));
  __syncthreads();
  const float m = bc;
  float ex[4];
  float s = 0.f;
#pragma unroll
  for (int q = 0; q < 4; q++) {
    const int t = tid + q * 256;
    ex[q] = (t < T_ && t < len) ? expf(v[q] - m) : 0.f;
    s += ex[q];
  }
#pragma unroll
  for (int off = 32; off; off >>= 1) s += __shfl_down(s, off);
  __syncthreads();
  if ((tid & 63) == 0) red[tid >> 6] = s;
  __syncthreads();
  if (tid == 0) bc2 = red[0] + red[1] + red[2] + red[3];
  __syncthreads();
  const float inv = 1.f / bc2;
#pragma unroll
  for (int q = 0; q < 4; q++) {
    const int t = tid + q * 256;
    if (t < T_) alpha[b * T_ + t] = ex[q] * inv;
  }
}

__global__ __launch_bounds__(256) void att_g(
    const float* __restrict__ alpha, const float* __restrict__ hb,
    float* __restrict__ g)
{
  const int idx = blockIdx.x * 256 + threadIdx.x;
  const int d = idx & (H2_ - 1), b = idx >> 10;
  const float* ab = alpha + b * T_;
  float acc = 0.f;
#pragma unroll 8
  for (int t = 0; t < T_; t++)
    acc = fmaf(ab[t], hb[((long)t * B_ + b) * H2_ + d], acc);
  g[idx] = acc;
}

__global__ __launch_bounds__(256) void dec_update(
    const float* __restrict__ rec, float* __restrict__ s, float* __restrict__ c)
{
  const int idx = blockIdx.x * 256 + threadIdx.x;
  if (idx >= B_ * H_) return;
  const int jj = idx & 511, b = idx >> 9;
  const float* r = rec + b * H4_;
  const float gi = r[jj], gf = r[jj + 512], gc = r[jj + 1024], go = r[jj + 1536];
  const float iv = tanhf(gi * 0.5f) * 0.5f + 0.5f;
  const float fv = tanhf(gf * 0.5f) * 0.5f + 0.5f;
  const float cg = tanhf(gc);
  const float ov = tanhf(go * 0.5f) * 0.5f + 0.5f;
  const float cn = fv * c[idx] + iv * cg;
  const float sn = ov * tanhf(cn);
  c[idx] = cn;
  s[idx] = sn;
}

extern "C" void kernel_launch(void* const* d_in, const int* in_sizes, int n_in,
                              void* d_out, int out_size, void* d_ws, size_t ws_size,
                              hipStream_t stream)
{
  const float* x       = (const float*)d_in[0];
  const int*   lengths = (const int*)  d_in[1];
  const float* target  = (const float*)d_in[2];
  const float* Wih0    = (const float*)d_in[3];
  const float* Whh0    = (const float*)d_in[4];
  const float* b0      = (const float*)d_in[5];
  const float* WihL    = (const float*)d_in[6];
  const float* WhhL    = (const float*)d_in[7];
  const float* bL      = (const float*)d_in[8];
  const float* W_se    = (const float*)d_in[9];
  const float* W_he    = (const float*)d_in[10];
  const float* b_he    = (const float*)d_in[11];
  const float* W_ee    = (const float*)d_in[12];
  const float* conv_w  = (const float*)d_in[13];
  const float* W_fe    = (const float*)d_in[14];
  const float* W_sy    = (const float*)d_in[15];
  const float* W_gy    = (const float*)d_in[16];
  const float* b_gy    = (const float*)d_in[17];
  const float* W_yy    = (const float*)d_in[18];
  const float* b_yy    = (const float*)d_in[19];
  const float* W_ys    = (const float*)d_in[20];
  const float* W_ss    = (const float*)d_in[21];
  const float* W_gs    = (const float*)d_in[22];
  const float* b_gs    = (const float*)d_in[23];
  float* out = (float*)d_out;

  // ---- workspace layout (~119.3 MB) ----
  float* bufA = (float*)d_ws;
  float* bufB = bufA + (size_t)T_ * B_ * H2_;
  float* gxc  = bufB + (size_t)T_ * B_ * H2_;
  float* gxcF = gxc;
  float* gxcB = gxc + (size_t)CH_ * B_ * H4_;
  float* he   = bufB;
  float* ysp  = gxc;
  float* st   = gxc + (size_t)2 * CH_ * B_ * H4_;
  float* hg0  = st;
  float* hg1  = hg0 + 2 * B_ * H_;
  float* cg   = hg1 + 2 * B_ * H_;
  float* sdec = cg + 2 * B_ * H_;
  float* cdec = sdec + B_ * H_;
  float* alpha= cdec + B_ * H_;
  float* conv = alpha + B_ * T_;
  float* ebuf = conv + B_ * 10 * T_;
  float* sebuf= ebuf + B_ * T_;
  float* gvec = sebuf + B_ * H2_;
  float* zvec = gvec + B_ * H2_;
  float* rec  = zvec + B_ * H_;
  unsigned* bar = (unsigned*)(rec + B_ * H4_ + 32);

  (void)hipMemsetAsync(bar, 0, 2048, stream);  // once; monotonic thereafter

  // ---- encoder ----
  transpose_x<<<(T_ * B_ * FEAT_ + 255) / 256, 256, 0, stream>>>(x, bufA);

  float* inb  = bufA;
  float* outb = bufB;
  for (int l = 0; l < 4; l++) {
    const int Kin = (l == 0) ? FEAT_ : H2_;
    const float *WihF, *WihB, *WhhF, *WhhB, *bF, *bB;
    if (l == 0) {
      WihF = Wih0;                 WihB = Wih0 + (size_t)H4_ * FEAT_;
      WhhF = Whh0;                 WhhB = Whh0 + (size_t)H4_ * H_;
      bF = b0;                     bB = b0 + H4_;
    } else {
      const size_t o = (size_t)(l - 1) * 2;
      WihF = WihL + o * H4_ * H2_; WihB = WihF + (size_t)H4_ * H2_;
      WhhF = WhhL + o * H4_ * H_;  WhhB = WhhF + (size_t)H4_ * H_;
      bF = bL + o * H4_;           bB = bF + H4_;
    }
    (void)hipMemsetAsync(hg0, 0, (size_t)3 * 2 * B_ * H_ * sizeof(float), stream);
    dim3 gg(H4_ / GBN, (CH_ * B_ + GBM - 1) / GBM, 2);  // (16, 7, 2)
    for (int c = 0; c < T_ / CH_; c++) {
      const int s0 = c * CH_;
      gemm_mfma_dual<<<gg, 256, 0, stream>>>(
          inb + (size_t)s0 * B_ * Kin, WihF, bF, gxcF,
          inb + (size_t)(T_ - s0 - CH_) * B_ * Kin, WihB, bB, gxcB,
          CH_ * B_, H4_, Kin, H4_);
      const int pbase = (l * (T_ / CH_) + c) * (CH_ - 1);
      lstm_compact<<<32, 256, 0, stream>>>(gxcF, gxcB, hg0, hg1, cg, outb,
                                           WhhF, WhhB, lengths, s0, pbase, bar);
    }
    float* tmp = inb; inb = outb; outb = tmp;
  }
  float* hb = inb;  // final encoder output = bufA

  // ---- decoder precompute (bf16 MFMA) ----
  {
    dim3 ghe(H2_ / GBN, (T_ * B_) / GBM);
    gemm_mfma<<<ghe, 256, 0, stream>>>(hb, W_he, b_he, he, T_ * B_, H2_, H2_, H2_);
    dim3 gys(H4_ / GBN, (B_ * NL_ + GBM - 1) / GBM);
    gemm_mfma<<<gys, 256, 0, stream>>>(target, W_ys, b_gs, ysp, B_ * NL_, H4_, CC_, H4_);
  }
  (void)hipMemsetAsync(sdec, 0, (size_t)(2 * B_ * H_ + B_ * T_) * sizeof(float), stream);

  // ---- decoder steps ----
  for (int step = 0; step < NL_; step++) {
    dec_conv<<<(B_ * 10 * T_ + 255) / 256, 256, 0, stream>>>(alpha, conv_w, conv);
    dotbn<0><<<(B_ * H2_) / 256, 256, 0, stream>>>(
        sdec, W_se, H_, nullptr, nullptr, 0, nullptr, 0, nullptr, sebuf, H2_, H2_);
    att_e<<<800, 256, 0, stream>>>(sebuf, he, conv, W_fe, W_ee, ebuf);
    att_softmax<<<B_, 256, 0, stream>>>(ebuf, lengths, alpha);
    att_g<<<(B_ * H2_) / 256, 256, 0, stream>>>(alpha, hb, gvec);
    dotbn<1><<<(B_ * H_) / 256, 256, 0, stream>>>(
        gvec, W_gy, H2_, sdec, W_sy, H_, nullptr, 0, b_gy, zvec, H_, H_);
    dotbn<0><<<(B_ * CC_ + 255) / 256, 256, 0, stream>>>(
        zvec, W_yy, H_, nullptr, nullptr, 0, nullptr, 0, b_yy,
        out + (size_t)step * CC_, NL_ * CC_, CC_);
    dotbn<0><<<(B_ * H4_) / 256, 256, 0, stream>>>(
        sdec, W_ss, H_, gvec, W_gs, H2_, ysp + (size_t)step * H4_, NL_ * H4_,
        nullptr, rec, H4_, H4_);
    dec_update<<<(B_ * H_) / 256, 256, 0, stream>>>(rec, sdec, cdec);
  }
}

// Round 12
// 55482.654 us; speedup vs baseline: 1.1130x; 1.0270x over previous
//
#include <hip/hip_runtime.h>
#include <math.h>

// Round 12: GEMM-under-recurrence fusion. CH=25; fused launch (160 WGs):
//   blocks 0-31  = R11 compact-MFMA recurrence for chunk c
//   blocks 32-159 = x-gate GEMM for chunk c+1 into ping-pong gate buffer
// (224 CUs were idle during the recurrence; the next chunk's GEMM is
// independent — only stream order serialized it. Kernel-boundary
// acquire/release publishes the gates, as in R2.)
// Encoder core, decoder, GEMM bodies otherwise unchanged from R11.

#define T_    800
#define B_    16
#define FEAT_ 120
#define H_    512
#define H2_   1024
#define H4_   2048
#define CC_   5000
#define NL_   100
#define CH_   25
#define NCH_  32
#define HPAD  536

typedef __attribute__((ext_vector_type(8))) short bf16x8;
typedef __attribute__((ext_vector_type(4))) float f32x4;

__device__ __forceinline__ void coh_store_f32(float* p, float v) {
  asm volatile("global_store_dword %0, %1, off sc0 sc1"
               :: "v"(p), "v"(v) : "memory");
}
__device__ __forceinline__ void coh_load8_f4(
    const float* p0, const float* p1, const float* p2, const float* p3,
    const float* p4, const float* p5, const float* p6, const float* p7,
    f32x4* o)
{
  asm volatile(
      "global_load_dwordx4 %0, %8, off sc0 sc1\n\t"
      "global_load_dwordx4 %1, %9, off sc0 sc1\n\t"
      "global_load_dwordx4 %2, %10, off sc0 sc1\n\t"
      "global_load_dwordx4 %3, %11, off sc0 sc1\n\t"
      "global_load_dwordx4 %4, %12, off sc0 sc1\n\t"
      "global_load_dwordx4 %5, %13, off sc0 sc1\n\t"
      "global_load_dwordx4 %6, %14, off sc0 sc1\n\t"
      "global_load_dwordx4 %7, %15, off sc0 sc1\n\t"
      "s_waitcnt vmcnt(0)"
      : "=&v"(o[0]), "=&v"(o[1]), "=&v"(o[2]), "=&v"(o[3]),
        "=&v"(o[4]), "=&v"(o[5]), "=&v"(o[6]), "=&v"(o[7])
      : "v"(p0), "v"(p1), "v"(p2), "v"(p3), "v"(p4), "v"(p5), "v"(p6), "v"(p7)
      : "memory");
}

__device__ __forceinline__ unsigned short f2bf(float f) {
  unsigned u = __builtin_bit_cast(unsigned, f);
  u += 0x7FFFu + ((u >> 16) & 1u);
  return (unsigned short)(u >> 16);
}
__device__ __forceinline__ float bf2f(unsigned short s) {
  return __builtin_bit_cast(float, (unsigned)s << 16);
}

// ---------------- bf16 MFMA GEMM tile (parameterized coords) ----------------
#define GBM 128
#define GBN 128
#define GBK 32
#define LDT 40

__device__ void mfma_gemm_tile(
    const float* __restrict__ A, const float* __restrict__ W,
    const float* __restrict__ bias, float* __restrict__ C,
    int M, int N, int K, int ldc, int bx, int by,
    unsigned short* As, unsigned short* Ws)
{
  const int tid = threadIdx.x;
  const int row0 = by * GBM, col0 = bx * GBN;
  const int lane = tid & 63, w = tid >> 6;
  const int wr = w >> 1, wc = w & 1;
  const int lm = lane & 15, lk8 = (lane >> 4) * 8;

  f32x4 acc[4][4];
#pragma unroll
  for (int i = 0; i < 4; i++)
#pragma unroll
    for (int j = 0; j < 4; j++) acc[i][j] = (f32x4)(0.f);

  const int sr = tid >> 1, skh = (tid & 1) * 16;

  for (int kt = 0; kt < K; kt += GBK) {
    {
      const int ar = row0 + sr;
      const int wrow = col0 + sr;
      unsigned short abuf[16], wbuf[16];
#pragma unroll
      for (int q = 0; q < 4; q++) {
        const int k0 = kt + skh + q * 4;
        float4 av = make_float4(0.f, 0.f, 0.f, 0.f);
        float4 wv = make_float4(0.f, 0.f, 0.f, 0.f);
        if (k0 + 4 <= K) {
          if (ar < M)   av = *(const float4*)(A + (size_t)ar * K + k0);
          if (wrow < N) wv = *(const float4*)(W + (size_t)wrow * K + k0);
        }
        abuf[q*4+0] = f2bf(av.x); abuf[q*4+1] = f2bf(av.y);
        abuf[q*4+2] = f2bf(av.z); abuf[q*4+3] = f2bf(av.w);
        wbuf[q*4+0] = f2bf(wv.x); wbuf[q*4+1] = f2bf(wv.y);
        wbuf[q*4+2] = f2bf(wv.z); wbuf[q*4+3] = f2bf(wv.w);
      }
      __syncthreads();
      *(uint4*)(As + sr * LDT + skh)     = *(uint4*)(abuf);
      *(uint4*)(As + sr * LDT + skh + 8) = *(uint4*)(abuf + 8);
      *(uint4*)(Ws + sr * LDT + skh)     = *(uint4*)(wbuf);
      *(uint4*)(Ws + sr * LDT + skh + 8) = *(uint4*)(wbuf + 8);
      __syncthreads();
    }
    bf16x8 af[4], bfv[4];
#pragma unroll
    for (int mi = 0; mi < 4; mi++)
      af[mi] = *(const bf16x8*)(As + (wr * 64 + mi * 16 + lm) * LDT + lk8);
#pragma unroll
    for (int ni = 0; ni < 4; ni++)
      bfv[ni] = *(const bf16x8*)(Ws + (wc * 64 + ni * 16 + lm) * LDT + lk8);
#pragma unroll
    for (int mi = 0; mi < 4; mi++)
#pragma unroll
      for (int ni = 0; ni < 4; ni++)
        acc[mi][ni] = __builtin_amdgcn_mfma_f32_16x16x32_bf16(
            af[mi], bfv[ni], acc[mi][ni], 0, 0, 0);
  }
#pragma unroll
  for (int mi = 0; mi < 4; mi++) {
#pragma unroll
    for (int reg = 0; reg < 4; reg++) {
      const int row = row0 + wr * 64 + mi * 16 + (lane >> 4) * 4 + reg;
      if (row < M) {
        float* crow = C + (size_t)row * ldc;
#pragma unroll
        for (int ni = 0; ni < 4; ni++) {
          const int col = col0 + wc * 64 + ni * 16 + lm;
          crow[col] = acc[mi][ni][reg] + (bias ? bias[col] : 0.f);
        }
      }
    }
  }
}

__global__ __launch_bounds__(256) void gemm_mfma(
    const float* __restrict__ A, const float* __restrict__ W,
    const float* __restrict__ bias, float* __restrict__ C,
    int M, int N, int K, int ldc)
{
  __shared__ unsigned short As[GBM * LDT];
  __shared__ unsigned short Ws[GBN * LDT];
  mfma_gemm_tile(A, W, bias, C, M, N, K, ldc, blockIdx.x, blockIdx.y, As, Ws);
}

__global__ __launch_bounds__(256) void gemm_mfma_dual(
    const float* __restrict__ A0, const float* __restrict__ W0,
    const float* __restrict__ b0, float* __restrict__ C0,
    const float* __restrict__ A1, const float* __restrict__ W1,
    const float* __restrict__ b1, float* __restrict__ C1,
    int M, int N, int K, int ldc)
{
  __shared__ unsigned short As[GBM * LDT];
  __shared__ unsigned short Ws[GBN * LDT];
  if (blockIdx.z == 0)
    mfma_gemm_tile(A0, W0, b0, C0, M, N, K, ldc, blockIdx.x, blockIdx.y, As, Ws);
  else
    mfma_gemm_tile(A1, W1, b1, C1, M, N, K, ldc, blockIdx.x, blockIdx.y, As, Ws);
}

__global__ __launch_bounds__(256) void transpose_x(
    const float* __restrict__ x, float* __restrict__ xt)
{
  const int i = blockIdx.x * 256 + threadIdx.x;
  if (i >= T_ * B_ * FEAT_) return;
  const int f = i % FEAT_;
  const int r = i / FEAT_;
  const int b = r % B_;
  const int t = r / B_;
  xt[i] = x[((long)b * T_ + t) * FEAT_ + f];
}

// ---------------- fused: compact-MFMA recurrence + next-chunk GEMM ---------
// grid = 160 WGs. blocks 0-31: recurrence (dir = b>>4, member = b&15).
// blocks 32-159: GEMM for chunk c+1 (bx = g&15, by = (g>>4)&3, bz = g>>6).
__global__ __launch_bounds__(256, 1) void lstm_fused(
    const float* __restrict__ gxF,   // [CH][B][4H] current chunk (fwd)
    const float* __restrict__ gxB,   // current chunk (bwd)
    float* __restrict__ gxFn,        // next chunk gates (write)
    float* __restrict__ gxBn,
    const float* __restrict__ inbF,  // next-chunk A ptrs (null on last chunk)
    const float* __restrict__ inbB,
    const float* __restrict__ WihF_, const float* __restrict__ WihB_,
    const float* __restrict__ bF_, const float* __restrict__ bB_, int Kin,
    float* __restrict__ hg0, float* __restrict__ hg1,
    float* __restrict__ cg, float* __restrict__ outb,
    const float* __restrict__ WhhF, const float* __restrict__ WhhB,
    const int* __restrict__ lengths, int s0, int pbase,
    unsigned* __restrict__ bar)
{
  __shared__ unsigned short h_hi[16][HPAD];
  __shared__ unsigned short h_lo[16][HPAD];
  __shared__ float gl[128 * 16];
  __shared__ float c_l[512];
  __shared__ int   len_l[16];
  __shared__ unsigned short As[GBM * LDT];
  __shared__ unsigned short Ws[GBN * LDT];

  if (blockIdx.x >= 32) {
    if (inbF == nullptr) return;
    const int g = blockIdx.x - 32;
    const int bx = g & 15, by = (g >> 4) & 3, bz = g >> 6;
    if (bz == 0)
      mfma_gemm_tile(inbF, WihF_, bF_, gxFn, CH_ * B_, H4_, Kin, H4_, bx, by, As, Ws);
    else
      mfma_gemm_tile(inbB, WihB_, bB_, gxBn, CH_ * B_, H4_, Kin, H4_, bx, by, As, Ws);
    return;
  }

  const int wg  = blockIdx.x;
  const int dir = wg >> 4;
  const int m   = wg & 15;
  const int tid = threadIdx.x;
  const int lane = tid & 63, w = tid >> 6;
  const int lrow = lane & 15, lko = (lane >> 4) * 8;

  if (tid < 16) len_l[tid] = lengths[tid];
  {
    const int eA = tid, eB = tid + 256;
    c_l[eA] = cg[(dir * 16 + (eA & 15)) * 512 + m * 32 + (eA >> 4)];
    c_l[eB] = cg[(dir * 16 + (eB & 15)) * 512 + m * 32 + (eB >> 4)];
  }

  const float* Whh = dir ? WhhB : WhhF;
  bf16x8 whi[2][16], wlo[2][16];
#pragma unroll
  for (int rt = 0; rt < 2; rt++) {
    const int row128 = (w * 2 + rt) * 16 + lrow;
    const int g = row128 >> 5, jj = row128 & 31;
    const float* wr = Whh + (size_t)(g * 512 + m * 32 + jj) * 512 + lko;
#pragma unroll
    for (int kt = 0; kt < 16; kt++) {
      unsigned short h8[8], l8[8];
#pragma unroll
      for (int i = 0; i < 8; i++) {
        const float v = wr[kt * 32 + i];
        h8[i] = f2bf(v);
        l8[i] = f2bf(v - bf2f(h8[i]));
      }
      whi[rt][kt] = *(bf16x8*)h8;
      wlo[rt][kt] = *(bf16x8*)l8;
    }
  }
  __syncthreads();

  unsigned* bcnt = bar + dir * 32;

  const int b0  = tid & 15;
  const int jjA = tid >> 4;
  const int jjB = jjA + 16;
  const int gb_ = tid >> 4;
  const int gk0 = (tid & 15) * 32;

  for (int ls = 0; ls < CH_; ls++) {
    const int s = s0 + ls;
    const int lt = dir ? (CH_ - 1 - ls) : ls;
    const float* gxp = (dir ? gxB : gxF) + ((size_t)lt * 16 + b0) * 2048 + m * 32;
    float ga[4], gb[4];
#pragma unroll
    for (int g = 0; g < 4; g++) { ga[g] = gxp[g * 512 + jjA]; gb[g] = gxp[g * 512 + jjB]; }

    if (s == 0) {
      const uint4 z = make_uint4(0, 0, 0, 0);
#pragma unroll
      for (int o = 0; o < 4; o++) {
        *(uint4*)&h_hi[gb_][gk0 + o * 8] = z;
        *(uint4*)&h_lo[gb_][gk0 + o * 8] = z;
      }
    } else {
      const float* hsrc = ((s & 1) ? hg1 : hg0) + (dir * 16 + gb_) * 512 + gk0;
      f32x4 hv[8];
      coh_load8_f4(hsrc, hsrc + 4, hsrc + 8, hsrc + 12,
                   hsrc + 16, hsrc + 20, hsrc + 24, hsrc + 28, hv);
      unsigned short sh[32], sl[32];
#pragma unroll
      for (int q = 0; q < 8; q++)
#pragma unroll
        for (int i = 0; i < 4; i++) {
          const float v = hv[q][i];
          const unsigned short hh = f2bf(v);
          sh[q * 4 + i] = hh;
          sl[q * 4 + i] = f2bf(v - bf2f(hh));
        }
#pragma unroll
      for (int o = 0; o < 4; o++) {
        *(uint4*)&h_hi[gb_][gk0 + o * 8] = *(uint4*)(sh + o * 8);
        *(uint4*)&h_lo[gb_][gk0 + o * 8] = *(uint4*)(sl + o * 8);
      }
    }
    __syncthreads();

    f32x4 acc[2];
    acc[0] = (f32x4)(0.f); acc[1] = (f32x4)(0.f);
#pragma unroll
    for (int kt = 0; kt < 16; kt++) {
      const bf16x8 bh = *(const bf16x8*)&h_hi[lrow][kt * 32 + lko];
      const bf16x8 bl = *(const bf16x8*)&h_lo[lrow][kt * 32 + lko];
#pragma unroll
      for (int rt = 0; rt < 2; rt++) {
        acc[rt] = __builtin_amdgcn_mfma_f32_16x16x32_bf16(whi[rt][kt], bh, acc[rt], 0, 0, 0);
        acc[rt] = __builtin_amdgcn_mfma_f32_16x16x32_bf16(wlo[rt][kt], bh, acc[rt], 0, 0, 0);
        acc[rt] = __builtin_amdgcn_mfma_f32_16x16x32_bf16(whi[rt][kt], bl, acc[rt], 0, 0, 0);
      }
    }
#pragma unroll
    for (int rt = 0; rt < 2; rt++) {
      const int rbase = (w * 2 + rt) * 16 + (lane >> 4) * 4;
#pragma unroll
      for (int r = 0; r < 4; r++)
        gl[(rbase + r) * 16 + lrow] = acc[rt][r];
    }
    __syncthreads();

    const int t = dir ? (T_ - 1 - s) : s;
    const bool mk = t < len_l[b0];
    float houtA, houtB, hnA, hnB;
    {
      const float gi = gl[(0 * 32 + jjA) * 16 + b0] + ga[0];
      const float gf = gl[(1 * 32 + jjA) * 16 + b0] + ga[1];
      const float gc = gl[(2 * 32 + jjA) * 16 + b0] + ga[2];
      const float go = gl[(3 * 32 + jjA) * 16 + b0] + ga[3];
      const float iv = 1.f / (1.f + expf(-gi));
      const float fv = 1.f / (1.f + expf(-gf));
      const float gv = tanhf(gc);
      const float ov = 1.f / (1.f + expf(-go));
      const float c_old = c_l[tid];
      const float h_old = bf2f(h_hi[b0][m * 32 + jjA]) + bf2f(h_lo[b0][m * 32 + jjA]);
      const float cn = fv * c_old + iv * gv;
      hnA = ov * tanhf(cn);
      c_l[tid] = mk ? cn : c_old;
      houtA = mk ? hnA : h_old;
    }
    {
      const float gi = gl[(0 * 32 + jjB) * 16 + b0] + gb[0];
      const float gf = gl[(1 * 32 + jjB) * 16 + b0] + gb[1];
      const float gc = gl[(2 * 32 + jjB) * 16 + b0] + gb[2];
      const float go = gl[(3 * 32 + jjB) * 16 + b0] + gb[3];
      const float iv = 1.f / (1.f + expf(-gi));
      const float fv = 1.f / (1.f + expf(-gf));
      const float gv = tanhf(gc);
      const float ov = 1.f / (1.f + expf(-go));
      const float c_old = c_l[tid + 256];
      const float h_old = bf2f(h_hi[b0][m * 32 + jjB]) + bf2f(h_lo[b0][m * 32 + jjB]);
      const float cn = fv * c_old + iv * gv;
      hnB = ov * tanhf(cn);
      c_l[tid + 256] = mk ? cn : c_old;
      houtB = mk ? hnB : h_old;
    }
    {
      float* hdst = ((s & 1) ? hg0 : hg1) + (dir * 16 + b0) * 512 + m * 32;
      coh_store_f32(&hdst[jjA], houtA);
      coh_store_f32(&hdst[jjB], houtB);
    }
    asm volatile("s_waitcnt vmcnt(0)" ::: "memory");
    __syncthreads();
    if (ls != CH_ - 1 && tid == 0) {
      __hip_atomic_fetch_add(bcnt, 1u, __ATOMIC_RELAXED, __HIP_MEMORY_SCOPE_AGENT);
      const unsigned tgt = (unsigned)(pbase + ls + 1) * 16u;
      long tries = 0;
      while (__hip_atomic_load(bcnt, __ATOMIC_RELAXED,
                               __HIP_MEMORY_SCOPE_AGENT) < tgt) {
        if (++tries > (1L << 22)) break;  // fail loud, never hang
      }
    }
    __syncthreads();
    outb[((size_t)t * 16 + b0) * H2_ + dir * 512 + m * 32 + jjA] = mk ? hnA : 0.f;
    outb[((size_t)t * 16 + b0) * H2_ + dir * 512 + m * 32 + jjB] = mk ? hnB : 0.f;
  }
  {
    const int eA = tid, eB = tid + 256;
    cg[(dir * 16 + (eA & 15)) * 512 + m * 32 + (eA >> 4)] = c_l[eA];
    cg[(dir * 16 + (eB & 15)) * 512 + m * 32 + (eB >> 4)] = c_l[eB];
  }
}

// ---------------- decoder kernels (byte-identical to R11) ----------------
template <int ACT>
__global__ __launch_bounds__(256) void dotbn(
    const float* __restrict__ S1, const float* __restrict__ W1, int K1,
    const float* __restrict__ S2, const float* __restrict__ W2, int K2,
    const float* __restrict__ pre, int preStride,
    const float* __restrict__ bias,
    float* __restrict__ outp, int outStride, int N)
{
  const int idx = blockIdx.x * 256 + threadIdx.x;
  if (idx >= N * B_) return;
  const int b = idx & 15, n = idx >> 4;
  float acc = bias ? bias[n] : 0.f;
  if (pre) acc += pre[(long)b * preStride + n];
  {
    const float* s = S1 + (long)b * K1;
    const float* w = W1 + (long)n * K1;
#pragma unroll 4
    for (int k = 0; k < K1; k += 4) {
      float4 sv = *(const float4*)(s + k);
      float4 wv = *(const float4*)(w + k);
      acc = fmaf(sv.x, wv.x, acc); acc = fmaf(sv.y, wv.y, acc);
      acc = fmaf(sv.z, wv.z, acc); acc = fmaf(sv.w, wv.w, acc);
    }
  }
  if (S2) {
    const float* s = S2 + (long)b * K2;
    const float* w = W2 + (long)n * K2;
#pragma unroll 4
    for (int k = 0; k < K2; k += 4) {
      float4 sv = *(const float4*)(s + k);
      float4 wv = *(const float4*)(w + k);
      acc = fmaf(sv.x, wv.x, acc); acc = fmaf(sv.y, wv.y, acc);
      acc = fmaf(sv.z, wv.z, acc); acc = fmaf(sv.w, wv.w, acc);
    }
  }
  if (ACT == 1) acc = tanhf(acc);
  outp[(long)b * outStride + n] = acc;
}

__global__ __launch_bounds__(256) void dec_conv(
    const float* __restrict__ alpha, const float* __restrict__ cw,
    float* __restrict__ conv)
{
  const int idx = blockIdx.x * 256 + threadIdx.x;
  if (idx >= B_ * 10 * T_) return;
  const int t = idx % T_;
  const int f = (idx / T_) % 10;
  const int b = idx / (10 * T_);
  const float* a = alpha + b * T_;
  const float* w = cw + f * 100;
  float acc = 0.f;
  const int k0 = (50 - t) > 0 ? (50 - t) : 0;
  const int k1 = (T_ + 50 - t) < 100 ? (T_ + 50 - t) : 100;
  for (int k = k0; k < k1; k++) acc = fmaf(a[t + k - 50], w[k], acc);
  conv[idx] = acc;
}

__global__ __launch_bounds__(256) void att_e(
    const float* __restrict__ se, const float* __restrict__ he,
    const float* __restrict__ conv, const float* __restrict__ W_fe,
    const float* __restrict__ W_ee, float* __restrict__ e)
{
  __shared__ float wfe[10240];
  __shared__ float ses[1024];
  __shared__ float wee[1024];
  __shared__ float red[4];
  const int wg = blockIdx.x;
  const int b = wg / 50, t0 = (wg % 50) * 16;
  const int tid = threadIdx.x;
  for (int i = tid; i < 10240; i += 256) wfe[i] = W_fe[i];
  for (int i = tid; i < 1024; i += 256) {
    ses[i] = se[b * H2_ + i];
    wee[i] = W_ee[i];
  }
  __syncthreads();
  for (int tt = 0; tt < 16; tt++) {
    const int t = t0 + tt;
    float cv[10];
#pragma unroll
    for (int f = 0; f < 10; f++) cv[f] = conv[(b * 10 + f) * T_ + t];
    const float* hrow = he + ((long)t * B_ + b) * H2_;
    float part = 0.f;
#pragma unroll
    for (int q = 0; q < 4; q++) {
      const int d = tid + q * 256;
      float loc = 0.f;
      const float* wf = &wfe[d * 10];
#pragma unroll
      for (int f = 0; f < 10; f++) loc = fmaf(cv[f], wf[f], loc);
      const float val = tanhf(ses[d] + hrow[d] + loc);
      part = fmaf(val, wee[d], part);
    }
#pragma unroll
    for (int off = 32; off; off >>= 1) part += __shfl_down(part, off);
    if ((tid & 63) == 0) red[tid >> 6] = part;
    __syncthreads();
    if (tid == 0) e[b * T_ + t] = red[0] + red[1] + red[2] + red[3];
    __syncthreads();
  }
}

__global__ __launch_bounds__(256) void att_softmax(
    const float* __restrict__ e, const int* __restrict__ lengths,
    float* __restrict__ alpha)
{
  __shared__ float red[4];
  __shared__ float bc, bc2;
  const int b = blockIdx.x, tid = threadIdx.x;
  const int len = lengths[b];
  float v[4];
  float mx = -1e30f;
#pragma unroll
  for (int q = 0; q < 4; q++) {
    const int t = tid + q * 256;
    v[q] = (t < T_) ? e[b * T_ + t] : -1e30f;
    mx = fmaxf(mx, v[q]);
  }
#pragma unroll
  for (int off = 32; off; off >>= 1) mx = fmaxf(mx, __shfl_down(mx, off));
  if ((tid & 63) == 0) red[tid >> 6] = mx;
  __syncthreads();
  if (tid == 0) bc = fmaxf(fmaxf(red[0], red[1]), fmaxf(red[2], red[3]));
  __syncthreads();
  const float m = bc;
  float ex[4];
  float s = 0.f;
#pragma unroll
  for (int q = 0; q < 4; q++) {
    const int t = tid + q * 256;
    ex[q] = (t < T_ && t < len) ? expf(v[q] - m) : 0.f;
    s += ex[q];
  }
#pragma unroll
  for (int off = 32; off; off >>= 1) s += __shfl_down(s, off);
  __syncthreads();
  if ((tid & 63) == 0) red[tid >> 6] = s;
  __syncthreads();
  if (tid == 0) bc2 = red[0] + red[1] + red[2] + red[3];
  __syncthreads();
  const float inv = 1.f / bc2;
#pragma unroll
  for (int q = 0; q < 4; q++) {
    const int t = tid + q * 256;
    if (t < T_) alpha[b * T_ + t] = ex[q] * inv;
  }
}

__global__ __launch_bounds__(256) void att_g(
    const float* __restrict__ alpha, const float* __restrict__ hb,
    float* __restrict__ g)
{
  const int idx = blockIdx.x * 256 + threadIdx.x;
  const int d = idx & (H2_ - 1), b = idx >> 10;
  const float* ab = alpha + b * T_;
  float acc = 0.f;
#pragma unroll 8
  for (int t = 0; t < T_; t++)
    acc = fmaf(ab[t], hb[((long)t * B_ + b) * H2_ + d], acc);
  g[idx] = acc;
}

__global__ __launch_bounds__(256) void dec_update(
    const float* __restrict__ rec, float* __restrict__ s, float* __restrict__ c)
{
  const int idx = blockIdx.x * 256 + threadIdx.x;
  if (idx >= B_ * H_) return;
  const int jj = idx & 511, b = idx >> 9;
  const float* r = rec + b * H4_;
  const float gi = r[jj], gf = r[jj + 512], gc = r[jj + 1024], go = r[jj + 1536];
  const float iv = tanhf(gi * 0.5f) * 0.5f + 0.5f;
  const float fv = tanhf(gf * 0.5f) * 0.5f + 0.5f;
  const float cg = tanhf(gc);
  const float ov = tanhf(go * 0.5f) * 0.5f + 0.5f;
  const float cn = fv * c[idx] + iv * cg;
  const float sn = ov * tanhf(cn);
  c[idx] = cn;
  s[idx] = sn;
}

extern "C" void kernel_launch(void* const* d_in, const int* in_sizes, int n_in,
                              void* d_out, int out_size, void* d_ws, size_t ws_size,
                              hipStream_t stream)
{
  const float* x       = (const float*)d_in[0];
  const int*   lengths = (const int*)  d_in[1];
  const float* target  = (const float*)d_in[2];
  const float* Wih0    = (const float*)d_in[3];
  const float* Whh0    = (const float*)d_in[4];
  const float* b0      = (const float*)d_in[5];
  const float* WihL    = (const float*)d_in[6];
  const float* WhhL    = (const float*)d_in[7];
  const float* bL      = (const float*)d_in[8];
  const float* W_se    = (const float*)d_in[9];
  const float* W_he    = (const float*)d_in[10];
  const float* b_he    = (const float*)d_in[11];
  const float* W_ee    = (const float*)d_in[12];
  const float* conv_w  = (const float*)d_in[13];
  const float* W_fe    = (const float*)d_in[14];
  const float* W_sy    = (const float*)d_in[15];
  const float* W_gy    = (const float*)d_in[16];
  const float* b_gy    = (const float*)d_in[17];
  const float* W_yy    = (const float*)d_in[18];
  const float* b_yy    = (const float*)d_in[19];
  const float* W_ys    = (const float*)d_in[20];
  const float* W_ss    = (const float*)d_in[21];
  const float* W_gs    = (const float*)d_in[22];
  const float* b_gs    = (const float*)d_in[23];
  float* out = (float*)d_out;

  // ---- workspace layout (~118 MB) ----
  const size_t CHB4 = (size_t)CH_ * B_ * H4_;      // one direction's gates
  float* bufA = (float*)d_ws;
  float* bufB = bufA + (size_t)T_ * B_ * H2_;
  float* gxc0 = bufB + (size_t)T_ * B_ * H2_;      // ping buffer [2*CHB4]
  float* gxc1 = gxc0 + 2 * CHB4;                   // pong buffer [2*CHB4]
  float* he   = bufB;                              // overlay post-encoder
  float* ysp  = gxc0;                              // overlay post-encoder (4*CHB4 = exact fit)
  float* st   = gxc1 + 2 * CHB4;
  float* hg0  = st;
  float* hg1  = hg0 + 2 * B_ * H_;
  float* cg   = hg1 + 2 * B_ * H_;
  float* sdec = cg + 2 * B_ * H_;
  float* cdec = sdec + B_ * H_;
  float* alpha= cdec + B_ * H_;
  float* conv = alpha + B_ * T_;
  float* ebuf = conv + B_ * 10 * T_;
  float* sebuf= ebuf + B_ * T_;
  float* gvec = sebuf + B_ * H2_;
  float* zvec = gvec + B_ * H2_;
  float* rec  = zvec + B_ * H_;
  unsigned* bar = (unsigned*)(rec + B_ * H4_ + 32);

  (void)hipMemsetAsync(bar, 0, 2048, stream);  // once; monotonic thereafter

  // ---- encoder ----
  transpose_x<<<(T_ * B_ * FEAT_ + 255) / 256, 256, 0, stream>>>(x, bufA);

  float* inb  = bufA;
  float* outb = bufB;
  float* gx[2] = {gxc0, gxc1};
  for (int l = 0; l < 4; l++) {
    const int Kin = (l == 0) ? FEAT_ : H2_;
    const float *WihF, *WihB, *WhhF, *WhhB, *bF, *bB;
    if (l == 0) {
      WihF = Wih0;                 WihB = Wih0 + (size_t)H4_ * FEAT_;
      WhhF = Whh0;                 WhhB = Whh0 + (size_t)H4_ * H_;
      bF = b0;                     bB = b0 + H4_;
    } else {
      const size_t o = (size_t)(l - 1) * 2;
      WihF = WihL + o * H4_ * H2_; WihB = WihF + (size_t)H4_ * H2_;
      WhhF = WhhL + o * H4_ * H_;  WhhB = WhhF + (size_t)H4_ * H_;
      bF = bL + o * H4_;           bB = bF + H4_;
    }
    (void)hipMemsetAsync(hg0, 0, (size_t)3 * 2 * B_ * H_ * sizeof(float), stream);
    // standalone GEMM seeds chunk 0
    {
      dim3 gg(H4_ / GBN, (CH_ * B_ + GBM - 1) / GBM, 2);  // (16, 4, 2)
      gemm_mfma_dual<<<gg, 256, 0, stream>>>(
          inb, WihF, bF, gx[0],
          inb + (size_t)(T_ - CH_) * B_ * Kin, WihB, bB, gx[0] + CHB4,
          CH_ * B_, H4_, Kin, H4_);
    }
    for (int c = 0; c < NCH_; c++) {
      const int cur = c & 1, nxt = cur ^ 1;
      const bool hasNext = (c + 1 < NCH_);
      const float* inbFn = hasNext ? inb + (size_t)(c + 1) * CH_ * B_ * Kin : nullptr;
      const float* inbBn = hasNext ? inb + (size_t)(T_ - (c + 2) * CH_) * B_ * Kin : nullptr;
      lstm_fused<<<160, 256, 0, stream>>>(
          gx[cur], gx[cur] + CHB4, gx[nxt], gx[nxt] + CHB4,
          inbFn, inbBn, WihF, WihB, bF, bB, Kin,
          hg0, hg1, cg, outb, WhhF, WhhB, lengths,
          c * CH_, (l * NCH_ + c) * (CH_ - 1), bar);
    }
    float* tmp = inb; inb = outb; outb = tmp;
  }
  float* hb = inb;  // final encoder output = bufA

  // ---- decoder precompute (bf16 MFMA) ----
  {
    dim3 ghe(H2_ / GBN, (T_ * B_) / GBM);
    gemm_mfma<<<ghe, 256, 0, stream>>>(hb, W_he, b_he, he, T_ * B_, H2_, H2_, H2_);
    dim3 gys(H4_ / GBN, (B_ * NL_ + GBM - 1) / GBM);
    gemm_mfma<<<gys, 256, 0, stream>>>(target, W_ys, b_gs, ysp, B_ * NL_, H4_, CC_, H4_);
  }
  (void)hipMemsetAsync(sdec, 0, (size_t)(2 * B_ * H_ + B_ * T_) * sizeof(float), stream);

  // ---- decoder steps ----
  for (int step = 0; step < NL_; step++) {
    dec_conv<<<(B_ * 10 * T_ + 255) / 256, 256, 0, stream>>>(alpha, conv_w, conv);
    dotbn<0><<<(B_ * H2_) / 256, 256, 0, stream>>>(
        sdec, W_se, H_, nullptr, nullptr, 0, nullptr, 0, nullptr, sebuf, H2_, H2_);
    att_e<<<800, 256, 0, stream>>>(sebuf, he, conv, W_fe, W_ee, ebuf);
    att_softmax<<<B_, 256, 0, stream>>>(ebuf, lengths, alpha);
    att_g<<<(B_ * H2_) / 256, 256, 0, stream>>>(alpha, hb, gvec);
    dotbn<1><<<(B_ * H_) / 256, 256, 0, stream>>>(
        gvec, W_gy, H2_, sdec, W_sy, H_, nullptr, 0, b_gy, zvec, H_, H_);
    dotbn<0><<<(B_ * CC_ + 255) / 256, 256, 0, stream>>>(
        zvec, W_yy, H_, nullptr, nullptr, 0, nullptr, 0, b_yy,
        out + (size_t)step * CC_, NL_ * CC_, CC_);
    dotbn<0><<<(B_ * H4_) / 256, 256, 0, stream>>>(
        sdec, W_ss, H_, gvec, W_gs, H2_, ysp + (size_t)step * H4_, NL_ * H4_,
        nullptr, rec, H4_, H4_);
    dec_update<<<(B_ * H_) / 256, 256, 0, stream>>>(rec, sdec, cdec);
  }
}

// Round 14
// 46799.945 us; speedup vs baseline: 1.3195x; 1.1855x over previous
//
#include <hip/hip_runtime.h>
#include <math.h>

// Round 14: R12 encoder verbatim (55.5ms known-good). Decoder consolidated
// 9 -> 5 launches/step: F1(conv||se), att_e, F3(softmax fused into att_g),
// F4(zvec||rec), F5(out||update). Softmax kept in LDS for the g-dot.

#define T_    800
#define B_    16
#define FEAT_ 120
#define H_    512
#define H2_   1024
#define H4_   2048
#define CC_   5000
#define NL_   100
#define CH_   25
#define NCH_  32
#define HPAD  536

typedef __attribute__((ext_vector_type(8))) short bf16x8;
typedef __attribute__((ext_vector_type(4))) float f32x4;

__device__ __forceinline__ void coh_store_f32(float* p, float v) {
  asm volatile("global_store_dword %0, %1, off sc0 sc1"
               :: "v"(p), "v"(v) : "memory");
}
__device__ __forceinline__ void coh_load8_f4(
    const float* p0, const float* p1, const float* p2, const float* p3,
    const float* p4, const float* p5, const float* p6, const float* p7,
    f32x4* o)
{
  asm volatile(
      "global_load_dwordx4 %0, %8, off sc0 sc1\n\t"
      "global_load_dwordx4 %1, %9, off sc0 sc1\n\t"
      "global_load_dwordx4 %2, %10, off sc0 sc1\n\t"
      "global_load_dwordx4 %3, %11, off sc0 sc1\n\t"
      "global_load_dwordx4 %4, %12, off sc0 sc1\n\t"
      "global_load_dwordx4 %5, %13, off sc0 sc1\n\t"
      "global_load_dwordx4 %6, %14, off sc0 sc1\n\t"
      "global_load_dwordx4 %7, %15, off sc0 sc1\n\t"
      "s_waitcnt vmcnt(0)"
      : "=&v"(o[0]), "=&v"(o[1]), "=&v"(o[2]), "=&v"(o[3]),
        "=&v"(o[4]), "=&v"(o[5]), "=&v"(o[6]), "=&v"(o[7])
      : "v"(p0), "v"(p1), "v"(p2), "v"(p3), "v"(p4), "v"(p5), "v"(p6), "v"(p7)
      : "memory");
}

__device__ __forceinline__ unsigned short f2bf(float f) {
  unsigned u = __builtin_bit_cast(unsigned, f);
  u += 0x7FFFu + ((u >> 16) & 1u);
  return (unsigned short)(u >> 16);
}
__device__ __forceinline__ float bf2f(unsigned short s) {
  return __builtin_bit_cast(float, (unsigned)s << 16);
}

// ---------------- bf16 MFMA GEMM tile ----------------
#define GBM 128
#define GBN 128
#define GBK 32
#define LDT 40

__device__ void mfma_gemm_tile(
    const float* __restrict__ A, const float* __restrict__ W,
    const float* __restrict__ bias, float* __restrict__ C,
    int M, int N, int K, int ldc, int bx, int by,
    unsigned short* As, unsigned short* Ws)
{
  const int tid = threadIdx.x;
  const int row0 = by * GBM, col0 = bx * GBN;
  const int lane = tid & 63, w = tid >> 6;
  const int wr = w >> 1, wc = w & 1;
  const int lm = lane & 15, lk8 = (lane >> 4) * 8;

  f32x4 acc[4][4];
#pragma unroll
  for (int i = 0; i < 4; i++)
#pragma unroll
    for (int j = 0; j < 4; j++) acc[i][j] = (f32x4)(0.f);

  const int sr = tid >> 1, skh = (tid & 1) * 16;

  for (int kt = 0; kt < K; kt += GBK) {
    {
      const int ar = row0 + sr;
      const int wrow = col0 + sr;
      unsigned short abuf[16], wbuf[16];
#pragma unroll
      for (int q = 0; q < 4; q++) {
        const int k0 = kt + skh + q * 4;
        float4 av = make_float4(0.f, 0.f, 0.f, 0.f);
        float4 wv = make_float4(0.f, 0.f, 0.f, 0.f);
        if (k0 + 4 <= K) {
          if (ar < M)   av = *(const float4*)(A + (size_t)ar * K + k0);
          if (wrow < N) wv = *(const float4*)(W + (size_t)wrow * K + k0);
        }
        abuf[q*4+0] = f2bf(av.x); abuf[q*4+1] = f2bf(av.y);
        abuf[q*4+2] = f2bf(av.z); abuf[q*4+3] = f2bf(av.w);
        wbuf[q*4+0] = f2bf(wv.x); wbuf[q*4+1] = f2bf(wv.y);
        wbuf[q*4+2] = f2bf(wv.z); wbuf[q*4+3] = f2bf(wv.w);
      }
      __syncthreads();
      *(uint4*)(As + sr * LDT + skh)     = *(uint4*)(abuf);
      *(uint4*)(As + sr * LDT + skh + 8) = *(uint4*)(abuf + 8);
      *(uint4*)(Ws + sr * LDT + skh)     = *(uint4*)(wbuf);
      *(uint4*)(Ws + sr * LDT + skh + 8) = *(uint4*)(wbuf + 8);
      __syncthreads();
    }
    bf16x8 af[4], bfv[4];
#pragma unroll
    for (int mi = 0; mi < 4; mi++)
      af[mi] = *(const bf16x8*)(As + (wr * 64 + mi * 16 + lm) * LDT + lk8);
#pragma unroll
    for (int ni = 0; ni < 4; ni++)
      bfv[ni] = *(const bf16x8*)(Ws + (wc * 64 + ni * 16 + lm) * LDT + lk8);
#pragma unroll
    for (int mi = 0; mi < 4; mi++)
#pragma unroll
      for (int ni = 0; ni < 4; ni++)
        acc[mi][ni] = __builtin_amdgcn_mfma_f32_16x16x32_bf16(
            af[mi], bfv[ni], acc[mi][ni], 0, 0, 0);
  }
#pragma unroll
  for (int mi = 0; mi < 4; mi++) {
#pragma unroll
    for (int reg = 0; reg < 4; reg++) {
      const int row = row0 + wr * 64 + mi * 16 + (lane >> 4) * 4 + reg;
      if (row < M) {
        float* crow = C + (size_t)row * ldc;
#pragma unroll
        for (int ni = 0; ni < 4; ni++) {
          const int col = col0 + wc * 64 + ni * 16 + lm;
          crow[col] = acc[mi][ni][reg] + (bias ? bias[col] : 0.f);
        }
      }
    }
  }
}

__global__ __launch_bounds__(256) void gemm_mfma(
    const float* __restrict__ A, const float* __restrict__ W,
    const float* __restrict__ bias, float* __restrict__ C,
    int M, int N, int K, int ldc)
{
  __shared__ unsigned short As[GBM * LDT];
  __shared__ unsigned short Ws[GBN * LDT];
  mfma_gemm_tile(A, W, bias, C, M, N, K, ldc, blockIdx.x, blockIdx.y, As, Ws);
}

__global__ __launch_bounds__(256) void gemm_mfma_dual(
    const float* __restrict__ A0, const float* __restrict__ W0,
    const float* __restrict__ b0, float* __restrict__ C0,
    const float* __restrict__ A1, const float* __restrict__ W1,
    const float* __restrict__ b1, float* __restrict__ C1,
    int M, int N, int K, int ldc)
{
  __shared__ unsigned short As[GBM * LDT];
  __shared__ unsigned short Ws[GBN * LDT];
  if (blockIdx.z == 0)
    mfma_gemm_tile(A0, W0, b0, C0, M, N, K, ldc, blockIdx.x, blockIdx.y, As, Ws);
  else
    mfma_gemm_tile(A1, W1, b1, C1, M, N, K, ldc, blockIdx.x, blockIdx.y, As, Ws);
}

__global__ __launch_bounds__(256) void transpose_x(
    const float* __restrict__ x, float* __restrict__ xt)
{
  const int i = blockIdx.x * 256 + threadIdx.x;
  if (i >= T_ * B_ * FEAT_) return;
  const int f = i % FEAT_;
  const int r = i / FEAT_;
  const int b = r % B_;
  const int t = r / B_;
  xt[i] = x[((long)b * T_ + t) * FEAT_ + f];
}

// ---------------- fused: compact-MFMA recurrence + next-chunk GEMM (R12) ---
__global__ __launch_bounds__(256, 1) void lstm_fused(
    const float* __restrict__ gxF, const float* __restrict__ gxB,
    float* __restrict__ gxFn, float* __restrict__ gxBn,
    const float* __restrict__ inbF, const float* __restrict__ inbB,
    const float* __restrict__ WihF_, const float* __restrict__ WihB_,
    const float* __restrict__ bF_, const float* __restrict__ bB_, int Kin,
    float* __restrict__ hg0, float* __restrict__ hg1,
    float* __restrict__ cg, float* __restrict__ outb,
    const float* __restrict__ WhhF, const float* __restrict__ WhhB,
    const int* __restrict__ lengths, int s0, int pbase,
    unsigned* __restrict__ bar)
{
  __shared__ unsigned short h_hi[16][HPAD];
  __shared__ unsigned short h_lo[16][HPAD];
  __shared__ float gl[128 * 16];
  __shared__ float c_l[512];
  __shared__ int   len_l[16];
  __shared__ unsigned short As[GBM * LDT];
  __shared__ unsigned short Ws[GBN * LDT];

  if (blockIdx.x >= 32) {
    if (inbF == nullptr) return;
    const int g = blockIdx.x - 32;
    const int bx = g & 15, by = (g >> 4) & 3, bz = g >> 6;
    if (bz == 0)
      mfma_gemm_tile(inbF, WihF_, bF_, gxFn, CH_ * B_, H4_, Kin, H4_, bx, by, As, Ws);
    else
      mfma_gemm_tile(inbB, WihB_, bB_, gxBn, CH_ * B_, H4_, Kin, H4_, bx, by, As, Ws);
    return;
  }

  const int wg  = blockIdx.x;
  const int dir = wg >> 4;
  const int m   = wg & 15;
  const int tid = threadIdx.x;
  const int lane = tid & 63, w = tid >> 6;
  const int lrow = lane & 15, lko = (lane >> 4) * 8;

  if (tid < 16) len_l[tid] = lengths[tid];
  {
    const int eA = tid, eB = tid + 256;
    c_l[eA] = cg[(dir * 16 + (eA & 15)) * 512 + m * 32 + (eA >> 4)];
    c_l[eB] = cg[(dir * 16 + (eB & 15)) * 512 + m * 32 + (eB >> 4)];
  }

  const float* Whh = dir ? WhhB : WhhF;
  bf16x8 whi[2][16], wlo[2][16];
#pragma unroll
  for (int rt = 0; rt < 2; rt++) {
    const int row128 = (w * 2 + rt) * 16 + lrow;
    const int g = row128 >> 5, jj = row128 & 31;
    const float* wr = Whh + (size_t)(g * 512 + m * 32 + jj) * 512 + lko;
#pragma unroll
    for (int kt = 0; kt < 16; kt++) {
      unsigned short h8[8], l8[8];
#pragma unroll
      for (int i = 0; i < 8; i++) {
        const float v = wr[kt * 32 + i];
        h8[i] = f2bf(v);
        l8[i] = f2bf(v - bf2f(h8[i]));
      }
      whi[rt][kt] = *(bf16x8*)h8;
      wlo[rt][kt] = *(bf16x8*)l8;
    }
  }
  __syncthreads();

  unsigned* bcnt = bar + dir * 32;

  const int b0  = tid & 15;
  const int jjA = tid >> 4;
  const int jjB = jjA + 16;
  const int gb_ = tid >> 4;
  const int gk0 = (tid & 15) * 32;

  for (int ls = 0; ls < CH_; ls++) {
    const int s = s0 + ls;
    const int lt = dir ? (CH_ - 1 - ls) : ls;
    const float* gxp = (dir ? gxB : gxF) + ((size_t)lt * 16 + b0) * 2048 + m * 32;
    float ga[4], gb[4];
#pragma unroll
    for (int g = 0; g < 4; g++) { ga[g] = gxp[g * 512 + jjA]; gb[g] = gxp[g * 512 + jjB]; }

    if (s == 0) {
      const uint4 z = make_uint4(0, 0, 0, 0);
#pragma unroll
      for (int o = 0; o < 4; o++) {
        *(uint4*)&h_hi[gb_][gk0 + o * 8] = z;
        *(uint4*)&h_lo[gb_][gk0 + o * 8] = z;
      }
    } else {
      const float* hsrc = ((s & 1) ? hg1 : hg0) + (dir * 16 + gb_) * 512 + gk0;
      f32x4 hv[8];
      coh_load8_f4(hsrc, hsrc + 4, hsrc + 8, hsrc + 12,
                   hsrc + 16, hsrc + 20, hsrc + 24, hsrc + 28, hv);
      unsigned short sh[32], sl[32];
#pragma unroll
      for (int q = 0; q < 8; q++)
#pragma unroll
        for (int i = 0; i < 4; i++) {
          const float v = hv[q][i];
          const unsigned short hh = f2bf(v);
          sh[q * 4 + i] = hh;
          sl[q * 4 + i] = f2bf(v - bf2f(hh));
        }
#pragma unroll
      for (int o = 0; o < 4; o++) {
        *(uint4*)&h_hi[gb_][gk0 + o * 8] = *(uint4*)(sh + o * 8);
        *(uint4*)&h_lo[gb_][gk0 + o * 8] = *(uint4*)(sl + o * 8);
      }
    }
    __syncthreads();

    f32x4 acc[2];
    acc[0] = (f32x4)(0.f); acc[1] = (f32x4)(0.f);
#pragma unroll
    for (int kt = 0; kt < 16; kt++) {
      const bf16x8 bh = *(const bf16x8*)&h_hi[lrow][kt * 32 + lko];
      const bf16x8 bl = *(const bf16x8*)&h_lo[lrow][kt * 32 + lko];
#pragma unroll
      for (int rt = 0; rt < 2; rt++) {
        acc[rt] = __builtin_amdgcn_mfma_f32_16x16x32_bf16(whi[rt][kt], bh, acc[rt], 0, 0, 0);
        acc[rt] = __builtin_amdgcn_mfma_f32_16x16x32_bf16(wlo[rt][kt], bh, acc[rt], 0, 0, 0);
        acc[rt] = __builtin_amdgcn_mfma_f32_16x16x32_bf16(whi[rt][kt], bl, acc[rt], 0, 0, 0);
      }
    }
#pragma unroll
    for (int rt = 0; rt < 2; rt++) {
      const int rbase = (w * 2 + rt) * 16 + (lane >> 4) * 4;
#pragma unroll
      for (int r = 0; r < 4; r++)
        gl[(rbase + r) * 16 + lrow] = acc[rt][r];
    }
    __syncthreads();

    const int t = dir ? (T_ - 1 - s) : s;
    const bool mk = t < len_l[b0];
    float houtA, houtB, hnA, hnB;
    {
      const float gi = gl[(0 * 32 + jjA) * 16 + b0] + ga[0];
      const float gf = gl[(1 * 32 + jjA) * 16 + b0] + ga[1];
      const float gc = gl[(2 * 32 + jjA) * 16 + b0] + ga[2];
      const float go = gl[(3 * 32 + jjA) * 16 + b0] + ga[3];
      const float iv = 1.f / (1.f + expf(-gi));
      const float fv = 1.f / (1.f + expf(-gf));
      const float gv = tanhf(gc);
      const float ov = 1.f / (1.f + expf(-go));
      const float c_old = c_l[tid];
      const float h_old = bf2f(h_hi[b0][m * 32 + jjA]) + bf2f(h_lo[b0][m * 32 + jjA]);
      const float cn = fv * c_old + iv * gv;
      hnA = ov * tanhf(cn);
      c_l[tid] = mk ? cn : c_old;
      houtA = mk ? hnA : h_old;
    }
    {
      const float gi = gl[(0 * 32 + jjB) * 16 + b0] + gb[0];
      const float gf = gl[(1 * 32 + jjB) * 16 + b0] + gb[1];
      const float gc = gl[(2 * 32 + jjB) * 16 + b0] + gb[2];
      const float go = gl[(3 * 32 + jjB) * 16 + b0] + gb[3];
      const float iv = 1.f / (1.f + expf(-gi));
      const float fv = 1.f / (1.f + expf(-gf));
      const float gv = tanhf(gc);
      const float ov = 1.f / (1.f + expf(-go));
      const float c_old = c_l[tid + 256];
      const float h_old = bf2f(h_hi[b0][m * 32 + jjB]) + bf2f(h_lo[b0][m * 32 + jjB]);
      const float cn = fv * c_old + iv * gv;
      hnB = ov * tanhf(cn);
      c_l[tid + 256] = mk ? cn : c_old;
      houtB = mk ? hnB : h_old;
    }
    {
      float* hdst = ((s & 1) ? hg0 : hg1) + (dir * 16 + b0) * 512 + m * 32;
      coh_store_f32(&hdst[jjA], houtA);
      coh_store_f32(&hdst[jjB], houtB);
    }
    asm volatile("s_waitcnt vmcnt(0)" ::: "memory");
    __syncthreads();
    if (ls != CH_ - 1 && tid == 0) {
      __hip_atomic_fetch_add(bcnt, 1u, __ATOMIC_RELAXED, __HIP_MEMORY_SCOPE_AGENT);
      const unsigned tgt = (unsigned)(pbase + ls + 1) * 16u;
      long tries = 0;
      while (__hip_atomic_load(bcnt, __ATOMIC_RELAXED,
                               __HIP_MEMORY_SCOPE_AGENT) < tgt) {
        if (++tries > (1L << 22)) break;  // fail loud, never hang
      }
    }
    __syncthreads();
    outb[((size_t)t * 16 + b0) * H2_ + dir * 512 + m * 32 + jjA] = mk ? hnA : 0.f;
    outb[((size_t)t * 16 + b0) * H2_ + dir * 512 + m * 32 + jjB] = mk ? hnB : 0.f;
  }
  {
    const int eA = tid, eB = tid + 256;
    cg[(dir * 16 + (eA & 15)) * 512 + m * 32 + (eA >> 4)] = c_l[eA];
    cg[(dir * 16 + (eB & 15)) * 512 + m * 32 + (eB >> 4)] = c_l[eB];
  }
}

// ---------------- consolidated decoder kernels ----------------
__device__ __forceinline__ float dot512(const float* s, const float* w) {
  float acc = 0.f;
#pragma unroll 4
  for (int k = 0; k < 512; k += 4) {
    float4 sv = *(const float4*)(s + k);
    float4 wv = *(const float4*)(w + k);
    acc = fmaf(sv.x, wv.x, acc); acc = fmaf(sv.y, wv.y, acc);
    acc = fmaf(sv.z, wv.z, acc); acc = fmaf(sv.w, wv.w, acc);
  }
  return acc;
}
__device__ __forceinline__ float dot1024(const float* s, const float* w) {
  float acc = 0.f;
#pragma unroll 4
  for (int k = 0; k < 1024; k += 4) {
    float4 sv = *(const float4*)(s + k);
    float4 wv = *(const float4*)(w + k);
    acc = fmaf(sv.x, wv.x, acc); acc = fmaf(sv.y, wv.y, acc);
    acc = fmaf(sv.z, wv.z, acc); acc = fmaf(sv.w, wv.w, acc);
  }
  return acc;
}

// F1: wg<500 conv ; wg>=500 se-projection (64 WGs)
__global__ __launch_bounds__(256) void dec_f1(
    const float* __restrict__ alpha, const float* __restrict__ cw,
    float* __restrict__ conv,
    const float* __restrict__ sdec, const float* __restrict__ W_se,
    float* __restrict__ sebuf)
{
  const int wg = blockIdx.x, tid = threadIdx.x;
  if (wg < 500) {
    const int idx = wg * 256 + tid;
    if (idx >= B_ * 10 * T_) return;
    const int t = idx % T_;
    const int f = (idx / T_) % 10;
    const int b = idx / (10 * T_);
    const float* a = alpha + b * T_;
    const float* w = cw + f * 100;
    float acc = 0.f;
    const int k0 = (50 - t) > 0 ? (50 - t) : 0;
    const int k1 = (T_ + 50 - t) < 100 ? (T_ + 50 - t) : 100;
    for (int k = k0; k < k1; k++) acc = fmaf(a[t + k - 50], w[k], acc);
    conv[idx] = acc;
  } else {
    const int idx = (wg - 500) * 256 + tid;     // 16384 = B * H2
    const int b = idx & 15, n = idx >> 4;
    sebuf[(size_t)b * H2_ + n] = dot512(sdec + (size_t)b * H_, W_se + (size_t)n * H_);
  }
}

// att_e (unchanged structure)
__global__ __launch_bounds__(256) void att_e(
    const float* __restrict__ se, const float* __restrict__ he,
    const float* __restrict__ conv, const float* __restrict__ W_fe,
    const float* __restrict__ W_ee, float* __restrict__ e)
{
  __shared__ float wfe[10240];
  __shared__ float ses[1024];
  __shared__ float wee[1024];
  __shared__ float red[4];
  const int wg = blockIdx.x;
  const int b = wg / 50, t0 = (wg % 50) * 16;
  const int tid = threadIdx.x;
  for (int i = tid; i < 10240; i += 256) wfe[i] = W_fe[i];
  for (int i = tid; i < 1024; i += 256) {
    ses[i] = se[b * H2_ + i];
    wee[i] = W_ee[i];
  }
  __syncthreads();
  for (int tt = 0; tt < 16; tt++) {
    const int t = t0 + tt;
    float cv[10];
#pragma unroll
    for (int f = 0; f < 10; f++) cv[f] = conv[(b * 10 + f) * T_ + t];
    const float* hrow = he + ((long)t * B_ + b) * H2_;
    float part = 0.f;
#pragma unroll
    for (int q = 0; q < 4; q++) {
      const int d = tid + q * 256;
      float loc = 0.f;
      const float* wf = &wfe[d * 10];
#pragma unroll
      for (int f = 0; f < 10; f++) loc = fmaf(cv[f], wf[f], loc);
      const float val = tanhf(ses[d] + hrow[d] + loc);
      part = fmaf(val, wee[d], part);
    }
#pragma unroll
    for (int off = 32; off; off >>= 1) part += __shfl_down(part, off);
    if ((tid & 63) == 0) red[tid >> 6] = part;
    __syncthreads();
    if (tid == 0) e[b * T_ + t] = red[0] + red[1] + red[2] + red[3];
    __syncthreads();
  }
}

// F3: 64 WGs = (b, d-group). Redundant per-WG softmax in LDS, then g-dot.
__global__ __launch_bounds__(256) void att_sg(
    const float* __restrict__ e, const int* __restrict__ lengths,
    const float* __restrict__ hb, float* __restrict__ alpha,
    float* __restrict__ g)
{
  __shared__ float al[800];
  __shared__ float red[4];
  __shared__ float bc, bc2;
  const int wg = blockIdx.x;
  const int b = wg >> 2, dg = wg & 3;
  const int tid = threadIdx.x;
  const int len = lengths[b];
  float v[4];
  float mx = -1e30f;
#pragma unroll
  for (int q = 0; q < 4; q++) {
    const int t = tid + q * 256;
    v[q] = (t < T_) ? e[b * T_ + t] : -1e30f;
    mx = fmaxf(mx, v[q]);
  }
#pragma unroll
  for (int off = 32; off; off >>= 1) mx = fmaxf(mx, __shfl_down(mx, off));
  if ((tid & 63) == 0) red[tid >> 6] = mx;
  __syncthreads();
  if (tid == 0) bc = fmaxf(fmaxf(red[0], red[1]), fmaxf(red[2], red[3]));
  __syncthreads();
  const float m = bc;
  float ex[4];
  float s = 0.f;
#pragma unroll
  for (int q = 0; q < 4; q++) {
    const int t = tid + q * 256;
    ex[q] = (t < T_ && t < len) ? expf(v[q] - m) : 0.f;
    s += ex[q];
  }
#pragma unroll
  for (int off = 32; off; off >>= 1) s += __shfl_down(s, off);
  __syncthreads();
  if ((tid & 63) == 0) red[tid >> 6] = s;
  __syncthreads();
  if (tid == 0) bc2 = red[0] + red[1] + red[2] + red[3];
  __syncthreads();
  const float inv = 1.f / bc2;
#pragma unroll
  for (int q = 0; q < 4; q++) {
    const int t = tid + q * 256;
    if (t < T_) al[t] = ex[q] * inv;
  }
  __syncthreads();
  if (dg == 0) {
#pragma unroll
    for (int q = 0; q < 4; q++) {
      const int t = tid + q * 256;
      if (t < T_) alpha[b * T_ + t] = al[t];
    }
  }
  // g-dot: d = dg*256 + tid
  const int d = dg * 256 + tid;
  const float* hp = hb + (size_t)b * H2_ + d;
  float acc = 0.f;
#pragma unroll 8
  for (int t = 0; t < T_; t++)
    acc = fmaf(al[t], hp[(size_t)t * B_ * H2_], acc);
  g[b * H2_ + d] = acc;
}

// F4: wg<32 zvec (tanh proj) ; wg>=32 rec (160 WGs total)
__global__ __launch_bounds__(256) void dec_f4(
    const float* __restrict__ gvec, const float* __restrict__ sdec,
    const float* __restrict__ W_gy, const float* __restrict__ W_sy,
    const float* __restrict__ b_gy, float* __restrict__ zvec,
    const float* __restrict__ W_ss, const float* __restrict__ W_gs,
    const float* __restrict__ pre, float* __restrict__ rec)
{
  const int wg = blockIdx.x, tid = threadIdx.x;
  if (wg < 32) {
    const int idx = wg * 256 + tid;             // 8192 = B * H
    const int b = idx & 15, n = idx >> 4;
    float acc = b_gy[n];
    acc += dot1024(gvec + (size_t)b * H2_, W_gy + (size_t)n * H2_);
    acc += dot512(sdec + (size_t)b * H_, W_sy + (size_t)n * H_);
    zvec[(size_t)b * H_ + n] = tanhf(acc);
  } else {
    const int idx = (wg - 32) * 256 + tid;      // 32768 = B * H4
    const int b = idx & 15, n = idx >> 4;
    float acc = pre[(size_t)b * NL_ * H4_ + n];
    acc += dot512(sdec + (size_t)b * H_, W_ss + (size_t)n * H_);
    acc += dot1024(gvec + (size_t)b * H2_, W_gs + (size_t)n * H2_);
    rec[(size_t)b * H4_ + n] = acc;
  }
}

// F5: wg<313 output GEMV ; wg>=313 state update (345 WGs total)
__global__ __launch_bounds__(256) void dec_f5(
    const float* __restrict__ zvec, const float* __restrict__ W_yy,
    const float* __restrict__ b_yy, float* __restrict__ outp,
    const float* __restrict__ rec, float* __restrict__ s,
    float* __restrict__ c)
{
  const int wg = blockIdx.x, tid = threadIdx.x;
  if (wg < 313) {
    const int idx = wg * 256 + tid;             // 80000 = B * CC
    if (idx >= B_ * CC_) return;
    const int b = idx & 15, n = idx >> 4;
    float acc = b_yy[n];
    acc += dot512(zvec + (size_t)b * H_, W_yy + (size_t)n * H_);
    outp[(size_t)b * NL_ * CC_ + n] = acc;
  } else {
    const int idx = (wg - 313) * 256 + tid;     // 8192 = B * H
    const int jj = idx & 511, b = idx >> 9;
    const float* r = rec + b * H4_;
    const float gi = r[jj], gf = r[jj + 512], gc = r[jj + 1024], go = r[jj + 1536];
    const float iv = tanhf(gi * 0.5f) * 0.5f + 0.5f;
    const float fv = tanhf(gf * 0.5f) * 0.5f + 0.5f;
    const float cgv = tanhf(gc);
    const float ov = tanhf(go * 0.5f) * 0.5f + 0.5f;
    const float cn = fv * c[idx] + iv * cgv;
    const float sn = ov * tanhf(cn);
    c[idx] = cn;
    s[idx] = sn;
  }
}

extern "C" void kernel_launch(void* const* d_in, const int* in_sizes, int n_in,
                              void* d_out, int out_size, void* d_ws, size_t ws_size,
                              hipStream_t stream)
{
  const float* x       = (const float*)d_in[0];
  const int*   lengths = (const int*)  d_in[1];
  const float* target  = (const float*)d_in[2];
  const float* Wih0    = (const float*)d_in[3];
  const float* Whh0    = (const float*)d_in[4];
  const float* b0      = (const float*)d_in[5];
  const float* WihL    = (const float*)d_in[6];
  const float* WhhL    = (const float*)d_in[7];
  const float* bL      = (const float*)d_in[8];
  const float* W_se    = (const float*)d_in[9];
  const float* W_he    = (const float*)d_in[10];
  const float* b_he    = (const float*)d_in[11];
  const float* W_ee    = (const float*)d_in[12];
  const float* conv_w  = (const float*)d_in[13];
  const float* W_fe    = (const float*)d_in[14];
  const float* W_sy    = (const float*)d_in[15];
  const float* W_gy    = (const float*)d_in[16];
  const float* b_gy    = (const float*)d_in[17];
  const float* W_yy    = (const float*)d_in[18];
  const float* b_yy    = (const float*)d_in[19];
  const float* W_ys    = (const float*)d_in[20];
  const float* W_ss    = (const float*)d_in[21];
  const float* W_gs    = (const float*)d_in[22];
  const float* b_gs    = (const float*)d_in[23];
  float* out = (float*)d_out;

  // ---- workspace layout (~118 MB) ----
  const size_t CHB4 = (size_t)CH_ * B_ * H4_;
  float* bufA = (float*)d_ws;
  float* bufB = bufA + (size_t)T_ * B_ * H2_;
  float* gxc0 = bufB + (size_t)T_ * B_ * H2_;
  float* gxc1 = gxc0 + 2 * CHB4;
  float* he   = bufB;
  float* ysp  = gxc0;
  float* st   = gxc1 + 2 * CHB4;
  float* hg0  = st;
  float* hg1  = hg0 + 2 * B_ * H_;
  float* cg   = hg1 + 2 * B_ * H_;
  float* sdec = cg + 2 * B_ * H_;
  float* cdec = sdec + B_ * H_;
  float* alpha= cdec + B_ * H_;
  float* conv = alpha + B_ * T_;
  float* ebuf = conv + B_ * 10 * T_;
  float* sebuf= ebuf + B_ * T_;
  float* gvec = sebuf + B_ * H2_;
  float* zvec = gvec + B_ * H2_;
  float* rec  = zvec + B_ * H_;
  unsigned* bar = (unsigned*)(rec + B_ * H4_ + 32);

  (void)hipMemsetAsync(bar, 0, 2048, stream);  // once; monotonic thereafter

  // ---- encoder (R12 verbatim) ----
  transpose_x<<<(T_ * B_ * FEAT_ + 255) / 256, 256, 0, stream>>>(x, bufA);

  float* inb  = bufA;
  float* outb = bufB;
  float* gx[2] = {gxc0, gxc1};
  for (int l = 0; l < 4; l++) {
    const int Kin = (l == 0) ? FEAT_ : H2_;
    const float *WihF, *WihB, *WhhF, *WhhB, *bF, *bB;
    if (l == 0) {
      WihF = Wih0;                 WihB = Wih0 + (size_t)H4_ * FEAT_;
      WhhF = Whh0;                 WhhB = Whh0 + (size_t)H4_ * H_;
      bF = b0;                     bB = b0 + H4_;
    } else {
      const size_t o = (size_t)(l - 1) * 2;
      WihF = WihL + o * H4_ * H2_; WihB = WihF + (size_t)H4_ * H2_;
      WhhF = WhhL + o * H4_ * H_;  WhhB = WhhF + (size_t)H4_ * H_;
      bF = bL + o * H4_;           bB = bF + H4_;
    }
    (void)hipMemsetAsync(hg0, 0, (size_t)3 * 2 * B_ * H_ * sizeof(float), stream);
    {
      dim3 gg(H4_ / GBN, (CH_ * B_ + GBM - 1) / GBM, 2);
      gemm_mfma_dual<<<gg, 256, 0, stream>>>(
          inb, WihF, bF, gx[0],
          inb + (size_t)(T_ - CH_) * B_ * Kin, WihB, bB, gx[0] + CHB4,
          CH_ * B_, H4_, Kin, H4_);
    }
    for (int c = 0; c < NCH_; c++) {
      const int cur = c & 1, nxt = cur ^ 1;
      const bool hasNext = (c + 1 < NCH_);
      const float* inbFn = hasNext ? inb + (size_t)(c + 1) * CH_ * B_ * Kin : nullptr;
      const float* inbBn = hasNext ? inb + (size_t)(T_ - (c + 2) * CH_) * B_ * Kin : nullptr;
      lstm_fused<<<160, 256, 0, stream>>>(
          gx[cur], gx[cur] + CHB4, gx[nxt], gx[nxt] + CHB4,
          inbFn, inbBn, WihF, WihB, bF, bB, Kin,
          hg0, hg1, cg, outb, WhhF, WhhB, lengths,
          c * CH_, (l * NCH_ + c) * (CH_ - 1), bar);
    }
    float* tmp = inb; inb = outb; outb = tmp;
  }
  float* hb = inb;

  // ---- decoder precompute (bf16 MFMA) ----
  {
    dim3 ghe(H2_ / GBN, (T_ * B_) / GBM);
    gemm_mfma<<<ghe, 256, 0, stream>>>(hb, W_he, b_he, he, T_ * B_, H2_, H2_, H2_);
    dim3 gys(H4_ / GBN, (B_ * NL_ + GBM - 1) / GBM);
    gemm_mfma<<<gys, 256, 0, stream>>>(target, W_ys, b_gs, ysp, B_ * NL_, H4_, CC_, H4_);
  }
  (void)hipMemsetAsync(sdec, 0, (size_t)(2 * B_ * H_ + B_ * T_) * sizeof(float), stream);

  // ---- decoder steps (5 launches each) ----
  for (int step = 0; step < NL_; step++) {
    dec_f1<<<564, 256, 0, stream>>>(alpha, conv_w, conv, sdec, W_se, sebuf);
    att_e<<<800, 256, 0, stream>>>(sebuf, he, conv, W_fe, W_ee, ebuf);
    att_sg<<<64, 256, 0, stream>>>(ebuf, lengths, hb, alpha, gvec);
    dec_f4<<<160, 256, 0, stream>>>(gvec, sdec, W_gy, W_sy, b_gy, zvec,
                                    W_ss, W_gs, ysp + (size_t)step * H4_, rec);
    dec_f5<<<345, 256, 0, stream>>>(zvec, W_yy, b_yy, out + (size_t)step * CC_,
                                    rec, sdec, cdec);
  }
}

// Round 16
// 43747.534 us; speedup vs baseline: 1.4115x; 1.0698x over previous
//
#include <hip/hip_runtime.h>
#include <math.h>

// Round 16: R15 deferral FIXED — no new memory, no overlap.
//   - ysp stored step-major [NL][B][4H] (GEMM epilogue row-remap mode 1)
//   - z[s>=1] overlaid into ysp's DEAD prefix at (s-1)*B*H (proof: s*BH <= 4s*BH)
//   - z[0] in a 32KB side buffer
//   - final output = two MFMA GEMMs with row-remap epilogues (modes 2,3)
// Encoder + decoder otherwise R14-identical.

#define T_    800
#define B_    16
#define FEAT_ 120
#define H_    512
#define H2_   1024
#define H4_   2048
#define CC_   5000
#define NL_   100
#define CH_   25
#define NCH_  32
#define HPAD  536

typedef __attribute__((ext_vector_type(8))) short bf16x8;
typedef __attribute__((ext_vector_type(4))) float f32x4;

__device__ __forceinline__ void coh_store_f32(float* p, float v) {
  asm volatile("global_store_dword %0, %1, off sc0 sc1"
               :: "v"(p), "v"(v) : "memory");
}
__device__ __forceinline__ void coh_load8_f4(
    const float* p0, const float* p1, const float* p2, const float* p3,
    const float* p4, const float* p5, const float* p6, const float* p7,
    f32x4* o)
{
  asm volatile(
      "global_load_dwordx4 %0, %8, off sc0 sc1\n\t"
      "global_load_dwordx4 %1, %9, off sc0 sc1\n\t"
      "global_load_dwordx4 %2, %10, off sc0 sc1\n\t"
      "global_load_dwordx4 %3, %11, off sc0 sc1\n\t"
      "global_load_dwordx4 %4, %12, off sc0 sc1\n\t"
      "global_load_dwordx4 %5, %13, off sc0 sc1\n\t"
      "global_load_dwordx4 %6, %14, off sc0 sc1\n\t"
      "global_load_dwordx4 %7, %15, off sc0 sc1\n\t"
      "s_waitcnt vmcnt(0)"
      : "=&v"(o[0]), "=&v"(o[1]), "=&v"(o[2]), "=&v"(o[3]),
        "=&v"(o[4]), "=&v"(o[5]), "=&v"(o[6]), "=&v"(o[7])
      : "v"(p0), "v"(p1), "v"(p2), "v"(p3), "v"(p4), "v"(p5), "v"(p6), "v"(p7)
      : "memory");
}

__device__ __forceinline__ unsigned short f2bf(float f) {
  unsigned u = __builtin_bit_cast(unsigned, f);
  u += 0x7FFFu + ((u >> 16) & 1u);
  return (unsigned short)(u >> 16);
}
__device__ __forceinline__ float bf2f(unsigned short s) {
  return __builtin_bit_cast(float, (unsigned)s << 16);
}

// ---------------- bf16 MFMA GEMM tile (with epilogue row remap) -----------
// rowmap: 0 identity | 1: (m%100)*16+m/100 | 2: (m&15)*100+(m>>4)+1 | 3: m*100
#define GBM 128
#define GBN 128
#define GBK 32
#define LDT 40

__device__ void mfma_gemm_tile(
    const float* __restrict__ A, const float* __restrict__ W,
    const float* __restrict__ bias, float* __restrict__ C,
    int M, int N, int K, int ldc, int bx, int by, int rowmap,
    unsigned short* As, unsigned short* Ws)
{
  const int tid = threadIdx.x;
  const int row0 = by * GBM, col0 = bx * GBN;
  const int lane = tid & 63, w = tid >> 6;
  const int wr = w >> 1, wc = w & 1;
  const int lm = lane & 15, lk8 = (lane >> 4) * 8;

  f32x4 acc[4][4];
#pragma unroll
  for (int i = 0; i < 4; i++)
#pragma unroll
    for (int j = 0; j < 4; j++) acc[i][j] = (f32x4)(0.f);

  const int sr = tid >> 1, skh = (tid & 1) * 16;

  for (int kt = 0; kt < K; kt += GBK) {
    {
      const int ar = row0 + sr;
      const int wrow = col0 + sr;
      unsigned short abuf[16], wbuf[16];
#pragma unroll
      for (int q = 0; q < 4; q++) {
        const int k0 = kt + skh + q * 4;
        float4 av = make_float4(0.f, 0.f, 0.f, 0.f);
        float4 wv = make_float4(0.f, 0.f, 0.f, 0.f);
        if (k0 + 4 <= K) {
          if (ar < M)   av = *(const float4*)(A + (size_t)ar * K + k0);
          if (wrow < N) wv = *(const float4*)(W + (size_t)wrow * K + k0);
        }
        abuf[q*4+0] = f2bf(av.x); abuf[q*4+1] = f2bf(av.y);
        abuf[q*4+2] = f2bf(av.z); abuf[q*4+3] = f2bf(av.w);
        wbuf[q*4+0] = f2bf(wv.x); wbuf[q*4+1] = f2bf(wv.y);
        wbuf[q*4+2] = f2bf(wv.z); wbuf[q*4+3] = f2bf(wv.w);
      }
      __syncthreads();
      *(uint4*)(As + sr * LDT + skh)     = *(uint4*)(abuf);
      *(uint4*)(As + sr * LDT + skh + 8) = *(uint4*)(abuf + 8);
      *(uint4*)(Ws + sr * LDT + skh)     = *(uint4*)(wbuf);
      *(uint4*)(Ws + sr * LDT + skh + 8) = *(uint4*)(wbuf + 8);
      __syncthreads();
    }
    bf16x8 af[4], bfv[4];
#pragma unroll
    for (int mi = 0; mi < 4; mi++)
      af[mi] = *(const bf16x8*)(As + (wr * 64 + mi * 16 + lm) * LDT + lk8);
#pragma unroll
    for (int ni = 0; ni < 4; ni++)
      bfv[ni] = *(const bf16x8*)(Ws + (wc * 64 + ni * 16 + lm) * LDT + lk8);
#pragma unroll
    for (int mi = 0; mi < 4; mi++)
#pragma unroll
      for (int ni = 0; ni < 4; ni++)
        acc[mi][ni] = __builtin_amdgcn_mfma_f32_16x16x32_bf16(
            af[mi], bfv[ni], acc[mi][ni], 0, 0, 0);
  }
#pragma unroll
  for (int mi = 0; mi < 4; mi++) {
#pragma unroll
    for (int reg = 0; reg < 4; reg++) {
      const int row = row0 + wr * 64 + mi * 16 + (lane >> 4) * 4 + reg;
      if (row < M) {
        int orow = row;
        if (rowmap == 1)      orow = (row % 100) * 16 + row / 100;
        else if (rowmap == 2) orow = (row & 15) * 100 + (row >> 4) + 1;
        else if (rowmap == 3) orow = row * 100;
        float* crow = C + (size_t)orow * ldc;
#pragma unroll
        for (int ni = 0; ni < 4; ni++) {
          const int col = col0 + wc * 64 + ni * 16 + lm;
          if (col < N) crow[col] = acc[mi][ni][reg] + (bias ? bias[col] : 0.f);
        }
      }
    }
  }
}

__global__ __launch_bounds__(256) void gemm_mfma(
    const float* __restrict__ A, const float* __restrict__ W,
    const float* __restrict__ bias, float* __restrict__ C,
    int M, int N, int K, int ldc, int rowmap)
{
  __shared__ unsigned short As[GBM * LDT];
  __shared__ unsigned short Ws[GBN * LDT];
  mfma_gemm_tile(A, W, bias, C, M, N, K, ldc, blockIdx.x, blockIdx.y, rowmap,
                 As, Ws);
}

__global__ __launch_bounds__(256) void gemm_mfma_dual(
    const float* __restrict__ A0, const float* __restrict__ W0,
    const float* __restrict__ b0, float* __restrict__ C0,
    const float* __restrict__ A1, const float* __restrict__ W1,
    const float* __restrict__ b1, float* __restrict__ C1,
    int M, int N, int K, int ldc)
{
  __shared__ unsigned short As[GBM * LDT];
  __shared__ unsigned short Ws[GBN * LDT];
  if (blockIdx.z == 0)
    mfma_gemm_tile(A0, W0, b0, C0, M, N, K, ldc, blockIdx.x, blockIdx.y, 0, As, Ws);
  else
    mfma_gemm_tile(A1, W1, b1, C1, M, N, K, ldc, blockIdx.x, blockIdx.y, 0, As, Ws);
}

__global__ __launch_bounds__(256) void transpose_x(
    const float* __restrict__ x, float* __restrict__ xt)
{
  const int i = blockIdx.x * 256 + threadIdx.x;
  if (i >= T_ * B_ * FEAT_) return;
  const int f = i % FEAT_;
  const int r = i / FEAT_;
  const int b = r % B_;
  const int t = r / B_;
  xt[i] = x[((long)b * T_ + t) * FEAT_ + f];
}

// ---------------- fused: compact-MFMA recurrence + next-chunk GEMM (R12) ---
__global__ __launch_bounds__(256, 1) void lstm_fused(
    const float* __restrict__ gxF, const float* __restrict__ gxB,
    float* __restrict__ gxFn, float* __restrict__ gxBn,
    const float* __restrict__ inbF, const float* __restrict__ inbB,
    const float* __restrict__ WihF_, const float* __restrict__ WihB_,
    const float* __restrict__ bF_, const float* __restrict__ bB_, int Kin,
    float* __restrict__ hg0, float* __restrict__ hg1,
    float* __restrict__ cg, float* __restrict__ outb,
    const float* __restrict__ WhhF, const float* __restrict__ WhhB,
    const int* __restrict__ lengths, int s0, int pbase,
    unsigned* __restrict__ bar)
{
  __shared__ unsigned short h_hi[16][HPAD];
  __shared__ unsigned short h_lo[16][HPAD];
  __shared__ float gl[128 * 16];
  __shared__ float c_l[512];
  __shared__ int   len_l[16];
  __shared__ unsigned short As[GBM * LDT];
  __shared__ unsigned short Ws[GBN * LDT];

  if (blockIdx.x >= 32) {
    if (inbF == nullptr) return;
    const int g = blockIdx.x - 32;
    const int bx = g & 15, by = (g >> 4) & 3, bz = g >> 6;
    if (bz == 0)
      mfma_gemm_tile(inbF, WihF_, bF_, gxFn, CH_ * B_, H4_, Kin, H4_, bx, by, 0, As, Ws);
    else
      mfma_gemm_tile(inbB, WihB_, bB_, gxBn, CH_ * B_, H4_, Kin, H4_, bx, by, 0, As, Ws);
    return;
  }

  const int wg  = blockIdx.x;
  const int dir = wg >> 4;
  const int m   = wg & 15;
  const int tid = threadIdx.x;
  const int lane = tid & 63, w = tid >> 6;
  const int lrow = lane & 15, lko = (lane >> 4) * 8;

  if (tid < 16) len_l[tid] = lengths[tid];
  {
    const int eA = tid, eB = tid + 256;
    c_l[eA] = cg[(dir * 16 + (eA & 15)) * 512 + m * 32 + (eA >> 4)];
    c_l[eB] = cg[(dir * 16 + (eB & 15)) * 512 + m * 32 + (eB >> 4)];
  }

  const float* Whh = dir ? WhhB : WhhF;
  bf16x8 whi[2][16], wlo[2][16];
#pragma unroll
  for (int rt = 0; rt < 2; rt++) {
    const int row128 = (w * 2 + rt) * 16 + lrow;
    const int g = row128 >> 5, jj = row128 & 31;
    const float* wr = Whh + (size_t)(g * 512 + m * 32 + jj) * 512 + lko;
#pragma unroll
    for (int kt = 0; kt < 16; kt++) {
      unsigned short h8[8], l8[8];
#pragma unroll
      for (int i = 0; i < 8; i++) {
        const float v = wr[kt * 32 + i];
        h8[i] = f2bf(v);
        l8[i] = f2bf(v - bf2f(h8[i]));
      }
      whi[rt][kt] = *(bf16x8*)h8;
      wlo[rt][kt] = *(bf16x8*)l8;
    }
  }
  __syncthreads();

  unsigned* bcnt = bar + dir * 32;

  const int b0  = tid & 15;
  const int jjA = tid >> 4;
  const int jjB = jjA + 16;
  const int gb_ = tid >> 4;
  const int gk0 = (tid & 15) * 32;

  for (int ls = 0; ls < CH_; ls++) {
    const int s = s0 + ls;
    const int lt = dir ? (CH_ - 1 - ls) : ls;
    const float* gxp = (dir ? gxB : gxF) + ((size_t)lt * 16 + b0) * 2048 + m * 32;
    float ga[4], gb[4];
#pragma unroll
    for (int g = 0; g < 4; g++) { ga[g] = gxp[g * 512 + jjA]; gb[g] = gxp[g * 512 + jjB]; }

    if (s == 0) {
      const uint4 z = make_uint4(0, 0, 0, 0);
#pragma unroll
      for (int o = 0; o < 4; o++) {
        *(uint4*)&h_hi[gb_][gk0 + o * 8] = z;
        *(uint4*)&h_lo[gb_][gk0 + o * 8] = z;
      }
    } else {
      const float* hsrc = ((s & 1) ? hg1 : hg0) + (dir * 16 + gb_) * 512 + gk0;
      f32x4 hv[8];
      coh_load8_f4(hsrc, hsrc + 4, hsrc + 8, hsrc + 12,
                   hsrc + 16, hsrc + 20, hsrc + 24, hsrc + 28, hv);
      unsigned short sh[32], sl[32];
#pragma unroll
      for (int q = 0; q < 8; q++)
#pragma unroll
        for (int i = 0; i < 4; i++) {
          const float v = hv[q][i];
          const unsigned short hh = f2bf(v);
          sh[q * 4 + i] = hh;
          sl[q * 4 + i] = f2bf(v - bf2f(hh));
        }
#pragma unroll
      for (int o = 0; o < 4; o++) {
        *(uint4*)&h_hi[gb_][gk0 + o * 8] = *(uint4*)(sh + o * 8);
        *(uint4*)&h_lo[gb_][gk0 + o * 8] = *(uint4*)(sl + o * 8);
      }
    }
    __syncthreads();

    f32x4 acc[2];
    acc[0] = (f32x4)(0.f); acc[1] = (f32x4)(0.f);
#pragma unroll
    for (int kt = 0; kt < 16; kt++) {
      const bf16x8 bh = *(const bf16x8*)&h_hi[lrow][kt * 32 + lko];
      const bf16x8 bl = *(const bf16x8*)&h_lo[lrow][kt * 32 + lko];
#pragma unroll
      for (int rt = 0; rt < 2; rt++) {
        acc[rt] = __builtin_amdgcn_mfma_f32_16x16x32_bf16(whi[rt][kt], bh, acc[rt], 0, 0, 0);
        acc[rt] = __builtin_amdgcn_mfma_f32_16x16x32_bf16(wlo[rt][kt], bh, acc[rt], 0, 0, 0);
        acc[rt] = __builtin_amdgcn_mfma_f32_16x16x32_bf16(whi[rt][kt], bl, acc[rt], 0, 0, 0);
      }
    }
#pragma unroll
    for (int rt = 0; rt < 2; rt++) {
      const int rbase = (w * 2 + rt) * 16 + (lane >> 4) * 4;
#pragma unroll
      for (int r = 0; r < 4; r++)
        gl[(rbase + r) * 16 + lrow] = acc[rt][r];
    }
    __syncthreads();

    const int t = dir ? (T_ - 1 - s) : s;
    const bool mk = t < len_l[b0];
    float houtA, houtB, hnA, hnB;
    {
      const float gi = gl[(0 * 32 + jjA) * 16 + b0] + ga[0];
      const float gf = gl[(1 * 32 + jjA) * 16 + b0] + ga[1];
      const float gc = gl[(2 * 32 + jjA) * 16 + b0] + ga[2];
      const float go = gl[(3 * 32 + jjA) * 16 + b0] + ga[3];
      const float iv = 1.f / (1.f + expf(-gi));
      const float fv = 1.f / (1.f + expf(-gf));
      const float gv = tanhf(gc);
      const float ov = 1.f / (1.f + expf(-go));
      const float c_old = c_l[tid];
      const float h_old = bf2f(h_hi[b0][m * 32 + jjA]) + bf2f(h_lo[b0][m * 32 + jjA]);
      const float cn = fv * c_old + iv * gv;
      hnA = ov * tanhf(cn);
      c_l[tid] = mk ? cn : c_old;
      houtA = mk ? hnA : h_old;
    }
    {
      const float gi = gl[(0 * 32 + jjB) * 16 + b0] + gb[0];
      const float gf = gl[(1 * 32 + jjB) * 16 + b0] + gb[1];
      const float gc = gl[(2 * 32 + jjB) * 16 + b0] + gb[2];
      const float go = gl[(3 * 32 + jjB) * 16 + b0] + gb[3];
      const float iv = 1.f / (1.f + expf(-gi));
      const float fv = 1.f / (1.f + expf(-gf));
      const float gv = tanhf(gc);
      const float ov = 1.f / (1.f + expf(-go));
      const float c_old = c_l[tid + 256];
      const float h_old = bf2f(h_hi[b0][m * 32 + jjB]) + bf2f(h_lo[b0][m * 32 + jjB]);
      const float cn = fv * c_old + iv * gv;
      hnB = ov * tanhf(cn);
      c_l[tid + 256] = mk ? cn : c_old;
      houtB = mk ? hnB : h_old;
    }
    {
      float* hdst = ((s & 1) ? hg0 : hg1) + (dir * 16 + b0) * 512 + m * 32;
      coh_store_f32(&hdst[jjA], houtA);
      coh_store_f32(&hdst[jjB], houtB);
    }
    asm volatile("s_waitcnt vmcnt(0)" ::: "memory");
    __syncthreads();
    if (ls != CH_ - 1 && tid == 0) {
      __hip_atomic_fetch_add(bcnt, 1u, __ATOMIC_RELAXED, __HIP_MEMORY_SCOPE_AGENT);
      const unsigned tgt = (unsigned)(pbase + ls + 1) * 16u;
      long tries = 0;
      while (__hip_atomic_load(bcnt, __ATOMIC_RELAXED,
                               __HIP_MEMORY_SCOPE_AGENT) < tgt) {
        if (++tries > (1L << 22)) break;  // fail loud, never hang
      }
    }
    __syncthreads();
    outb[((size_t)t * 16 + b0) * H2_ + dir * 512 + m * 32 + jjA] = mk ? hnA : 0.f;
    outb[((size_t)t * 16 + b0) * H2_ + dir * 512 + m * 32 + jjB] = mk ? hnB : 0.f;
  }
  {
    const int eA = tid, eB = tid + 256;
    cg[(dir * 16 + (eA & 15)) * 512 + m * 32 + (eA >> 4)] = c_l[eA];
    cg[(dir * 16 + (eB & 15)) * 512 + m * 32 + (eB >> 4)] = c_l[eB];
  }
}

// ---------------- consolidated decoder kernels ----------------
__device__ __forceinline__ float dot512(const float* s, const float* w) {
  float acc = 0.f;
#pragma unroll 4
  for (int k = 0; k < 512; k += 4) {
    float4 sv = *(const float4*)(s + k);
    float4 wv = *(const float4*)(w + k);
    acc = fmaf(sv.x, wv.x, acc); acc = fmaf(sv.y, wv.y, acc);
    acc = fmaf(sv.z, wv.z, acc); acc = fmaf(sv.w, wv.w, acc);
  }
  return acc;
}
__device__ __forceinline__ float dot1024(const float* s, const float* w) {
  float acc = 0.f;
#pragma unroll 4
  for (int k = 0; k < 1024; k += 4) {
    float4 sv = *(const float4*)(s + k);
    float4 wv = *(const float4*)(w + k);
    acc = fmaf(sv.x, wv.x, acc); acc = fmaf(sv.y, wv.y, acc);
    acc = fmaf(sv.z, wv.z, acc); acc = fmaf(sv.w, wv.w, acc);
  }
  return acc;
}

// F1: wg<500 conv ; wg>=500 se-projection
__global__ __launch_bounds__(256) void dec_f1(
    const float* __restrict__ alpha, const float* __restrict__ cw,
    float* __restrict__ conv,
    const float* __restrict__ sdec, const float* __restrict__ W_se,
    float* __restrict__ sebuf)
{
  const int wg = blockIdx.x, tid = threadIdx.x;
  if (wg < 500) {
    const int idx = wg * 256 + tid;
    if (idx >= B_ * 10 * T_) return;
    const int t = idx % T_;
    const int f = (idx / T_) % 10;
    const int b = idx / (10 * T_);
    const float* a = alpha + b * T_;
    const float* w = cw + f * 100;
    float acc = 0.f;
    const int k0 = (50 - t) > 0 ? (50 - t) : 0;
    const int k1 = (T_ + 50 - t) < 100 ? (T_ + 50 - t) : 100;
    for (int k = k0; k < k1; k++) acc = fmaf(a[t + k - 50], w[k], acc);
    conv[idx] = acc;
  } else {
    const int idx = (wg - 500) * 256 + tid;
    const int b = idx & 15, n = idx >> 4;
    sebuf[(size_t)b * H2_ + n] = dot512(sdec + (size_t)b * H_, W_se + (size_t)n * H_);
  }
}

__global__ __launch_bounds__(256) void att_e(
    const float* __restrict__ se, const float* __restrict__ he,
    const float* __restrict__ conv, const float* __restrict__ W_fe,
    const float* __restrict__ W_ee, float* __restrict__ e)
{
  __shared__ float wfe[10240];
  __shared__ float ses[1024];
  __shared__ float wee[1024];
  __shared__ float red[4];
  const int wg = blockIdx.x;
  const int b = wg / 50, t0 = (wg % 50) * 16;
  const int tid = threadIdx.x;
  for (int i = tid; i < 10240; i += 256) wfe[i] = W_fe[i];
  for (int i = tid; i < 1024; i += 256) {
    ses[i] = se[b * H2_ + i];
    wee[i] = W_ee[i];
  }
  __syncthreads();
  for (int tt = 0; tt < 16; tt++) {
    const int t = t0 + tt;
    float cv[10];
#pragma unroll
    for (int f = 0; f < 10; f++) cv[f] = conv[(b * 10 + f) * T_ + t];
    const float* hrow = he + ((long)t * B_ + b) * H2_;
    float part = 0.f;
#pragma unroll
    for (int q = 0; q < 4; q++) {
      const int d = tid + q * 256;
      float loc = 0.f;
      const float* wf = &wfe[d * 10];
#pragma unroll
      for (int f = 0; f < 10; f++) loc = fmaf(cv[f], wf[f], loc);
      const float val = tanhf(ses[d] + hrow[d] + loc);
      part = fmaf(val, wee[d], part);
    }
#pragma unroll
    for (int off = 32; off; off >>= 1) part += __shfl_down(part, off);
    if ((tid & 63) == 0) red[tid >> 6] = part;
    __syncthreads();
    if (tid == 0) e[b * T_ + t] = red[0] + red[1] + red[2] + red[3];
    __syncthreads();
  }
}

// F3: 64 WGs = (b, d-group). Redundant per-WG softmax in LDS, then g-dot.
__global__ __launch_bounds__(256) void att_sg(
    const float* __restrict__ e, const int* __restrict__ lengths,
    const float* __restrict__ hb, float* __restrict__ alpha,
    float* __restrict__ g)
{
  __shared__ float al[800];
  __shared__ float red[4];
  __shared__ float bc, bc2;
  const int wg = blockIdx.x;
  const int b = wg >> 2, dg = wg & 3;
  const int tid = threadIdx.x;
  const int len = lengths[b];
  float v[4];
  float mx = -1e30f;
#pragma unroll
  for (int q = 0; q < 4; q++) {
    const int t = tid + q * 256;
    v[q] = (t < T_) ? e[b * T_ + t] : -1e30f;
    mx = fmaxf(mx, v[q]);
  }
#pragma unroll
  for (int off = 32; off; off >>= 1) mx = fmaxf(mx, __shfl_down(mx, off));
  if ((tid & 63) == 0) red[tid >> 6] = mx;
  __syncthreads();
  if (tid == 0) bc = fmaxf(fmaxf(red[0], red[1]), fmaxf(red[2], red[3]));
  __syncthreads();
  const float m = bc;
  float ex[4];
  float s = 0.f;
#pragma unroll
  for (int q = 0; q < 4; q++) {
    const int t = tid + q * 256;
    ex[q] = (t < T_ && t < len) ? expf(v[q] - m) : 0.f;
    s += ex[q];
  }
#pragma unroll
  for (int off = 32; off; off >>= 1) s += __shfl_down(s, off);
  __syncthreads();
  if ((tid & 63) == 0) red[tid >> 6] = s;
  __syncthreads();
  if (tid == 0) bc2 = red[0] + red[1] + red[2] + red[3];
  __syncthreads();
  const float inv = 1.f / bc2;
#pragma unroll
  for (int q = 0; q < 4; q++) {
    const int t = tid + q * 256;
    if (t < T_) al[t] = ex[q] * inv;
  }
  __syncthreads();
  if (dg == 0) {
#pragma unroll
    for (int q = 0; q < 4; q++) {
      const int t = tid + q * 256;
      if (t < T_) alpha[b * T_ + t] = al[t];
    }
  }
  const int d = dg * 256 + tid;
  const float* hp = hb + (size_t)b * H2_ + d;
  float acc = 0.f;
#pragma unroll 8
  for (int t = 0; t < T_; t++)
    acc = fmaf(al[t], hp[(size_t)t * B_ * H2_], acc);
  g[b * H2_ + d] = acc;
}

// F4: wg<32 z (tanh proj -> zdst[b][H]) ; wg>=32 rec (pre step-major)
__global__ __launch_bounds__(256) void dec_f4(
    const float* __restrict__ gvec, const float* __restrict__ sdec,
    const float* __restrict__ W_gy, const float* __restrict__ W_sy,
    const float* __restrict__ b_gy, float* __restrict__ zdst,
    const float* __restrict__ W_ss, const float* __restrict__ W_gs,
    const float* __restrict__ pre, float* __restrict__ rec)
{
  const int wg = blockIdx.x, tid = threadIdx.x;
  if (wg < 32) {
    const int idx = wg * 256 + tid;             // 8192 = B * H
    const int b = idx & 15, n = idx >> 4;
    float acc = b_gy[n];
    acc += dot1024(gvec + (size_t)b * H2_, W_gy + (size_t)n * H2_);
    acc += dot512(sdec + (size_t)b * H_, W_sy + (size_t)n * H_);
    zdst[(size_t)b * H_ + n] = tanhf(acc);
  } else {
    const int idx = (wg - 32) * 256 + tid;      // 32768 = B * H4
    const int b = idx & 15, n = idx >> 4;
    float acc = pre[(size_t)b * H4_ + n];       // step-major: pre = ysp + step*B*H4
    acc += dot512(sdec + (size_t)b * H_, W_ss + (size_t)n * H_);
    acc += dot1024(gvec + (size_t)b * H2_, W_gs + (size_t)n * H2_);
    rec[(size_t)b * H4_ + n] = acc;
  }
}

// F5: state update only (32 WGs)
__global__ __launch_bounds__(256) void dec_f5(
    const float* __restrict__ rec, float* __restrict__ s, float* __restrict__ c)
{
  const int idx = blockIdx.x * 256 + threadIdx.x;   // 8192 = B * H
  const int jj = idx & 511, b = idx >> 9;
  const float* r = rec + b * H4_;
  const float gi = r[jj], gf = r[jj + 512], gc = r[jj + 1024], go = r[jj + 1536];
  const float iv = tanhf(gi * 0.5f) * 0.5f + 0.5f;
  const float fv = tanhf(gf * 0.5f) * 0.5f + 0.5f;
  const float cgv = tanhf(gc);
  const float ov = tanhf(go * 0.5f) * 0.5f + 0.5f;
  const float cn = fv * c[idx] + iv * cgv;
  const float sn = ov * tanhf(cn);
  c[idx] = cn;
  s[idx] = sn;
}

extern "C" void kernel_launch(void* const* d_in, const int* in_sizes, int n_in,
                              void* d_out, int out_size, void* d_ws, size_t ws_size,
                              hipStream_t stream)
{
  const float* x       = (const float*)d_in[0];
  const int*   lengths = (const int*)  d_in[1];
  const float* target  = (const float*)d_in[2];
  const float* Wih0    = (const float*)d_in[3];
  const float* Whh0    = (const float*)d_in[4];
  const float* b0      = (const float*)d_in[5];
  const float* WihL    = (const float*)d_in[6];
  const float* WhhL    = (const float*)d_in[7];
  const float* bL      = (const float*)d_in[8];
  const float* W_se    = (const float*)d_in[9];
  const float* W_he    = (const float*)d_in[10];
  const float* b_he    = (const float*)d_in[11];
  const float* W_ee    = (const float*)d_in[12];
  const float* conv_w  = (const float*)d_in[13];
  const float* W_fe    = (const float*)d_in[14];
  const float* W_sy    = (const float*)d_in[15];
  const float* W_gy    = (const float*)d_in[16];
  const float* b_gy    = (const float*)d_in[17];
  const float* W_yy    = (const float*)d_in[18];
  const float* b_yy    = (const float*)d_in[19];
  const float* W_ys    = (const float*)d_in[20];
  const float* W_ss    = (const float*)d_in[21];
  const float* W_gs    = (const float*)d_in[22];
  const float* b_gs    = (const float*)d_in[23];
  float* out = (float*)d_out;

  // ---- workspace layout (~119.1 MB + 32KB) ----
  const size_t CHB4 = (size_t)CH_ * B_ * H4_;
  const size_t BH   = (size_t)B_ * H_;
  float* bufA = (float*)d_ws;
  float* bufB = bufA + (size_t)T_ * B_ * H2_;
  float* gxc0 = bufB + (size_t)T_ * B_ * H2_;
  float* gxc1 = gxc0 + 2 * CHB4;
  float* he   = bufB;
  float* ysp  = gxc0;                    // [NL][B][H4] step-major (4*CHB4)
  float* st   = gxc1 + 2 * CHB4;
  float* hg0  = st;
  float* hg1  = hg0 + 2 * B_ * H_;
  float* cg   = hg1 + 2 * B_ * H_;
  float* sdec = cg + 2 * B_ * H_;
  float* cdec = sdec + B_ * H_;
  float* alpha= cdec + B_ * H_;
  float* conv = alpha + B_ * T_;
  float* ebuf = conv + B_ * 10 * T_;
  float* sebuf= ebuf + B_ * T_;
  float* gvec = sebuf + B_ * H2_;
  float* rec  = gvec + B_ * H2_;
  unsigned* bar = (unsigned*)(rec + B_ * H4_ + 32);
  float* z0buf = (float*)(bar + 768);    // [B][H] for step 0 (32KB)

  (void)hipMemsetAsync(bar, 0, 2048, stream);  // once; monotonic thereafter

  // ---- encoder (R12 verbatim) ----
  transpose_x<<<(T_ * B_ * FEAT_ + 255) / 256, 256, 0, stream>>>(x, bufA);

  float* inb  = bufA;
  float* outb = bufB;
  float* gx[2] = {gxc0, gxc1};
  for (int l = 0; l < 4; l++) {
    const int Kin = (l == 0) ? FEAT_ : H2_;
    const float *WihF, *WihB, *WhhF, *WhhB, *bF, *bB;
    if (l == 0) {
      WihF = Wih0;                 WihB = Wih0 + (size_t)H4_ * FEAT_;
      WhhF = Whh0;                 WhhB = Whh0 + (size_t)H4_ * H_;
      bF = b0;                     bB = b0 + H4_;
    } else {
      const size_t o = (size_t)(l - 1) * 2;
      WihF = WihL + o * H4_ * H2_; WihB = WihF + (size_t)H4_ * H2_;
      WhhF = WhhL + o * H4_ * H_;  WhhB = WhhF + (size_t)H4_ * H_;
      bF = bL + o * H4_;           bB = bF + H4_;
    }
    (void)hipMemsetAsync(hg0, 0, (size_t)3 * 2 * B_ * H_ * sizeof(float), stream);
    {
      dim3 gg(H4_ / GBN, (CH_ * B_ + GBM - 1) / GBM, 2);
      gemm_mfma_dual<<<gg, 256, 0, stream>>>(
          inb, WihF, bF, gx[0],
          inb + (size_t)(T_ - CH_) * B_ * Kin, WihB, bB, gx[0] + CHB4,
          CH_ * B_, H4_, Kin, H4_);
    }
    for (int c = 0; c < NCH_; c++) {
      const int cur = c & 1, nxt = cur ^ 1;
      const bool hasNext = (c + 1 < NCH_);
      const float* inbFn = hasNext ? inb + (size_t)(c + 1) * CH_ * B_ * Kin : nullptr;
      const float* inbBn = hasNext ? inb + (size_t)(T_ - (c + 2) * CH_) * B_ * Kin : nullptr;
      lstm_fused<<<160, 256, 0, stream>>>(
          gx[cur], gx[cur] + CHB4, gx[nxt], gx[nxt] + CHB4,
          inbFn, inbBn, WihF, WihB, bF, bB, Kin,
          hg0, hg1, cg, outb, WhhF, WhhB, lengths,
          c * CH_, (l * NCH_ + c) * (CH_ - 1), bar);
    }
    float* tmp = inb; inb = outb; outb = tmp;
  }
  float* hb = inb;

  // ---- decoder precompute ----
  {
    dim3 ghe(H2_ / GBN, (T_ * B_) / GBM);
    gemm_mfma<<<ghe, 256, 0, stream>>>(hb, W_he, b_he, he, T_ * B_, H2_, H2_, H2_, 0);
    // ysp step-major: row m = b*NL+step  ->  orow = step*B + b  (rowmap 1)
    dim3 gys(H4_ / GBN, (B_ * NL_ + GBM - 1) / GBM);
    gemm_mfma<<<gys, 256, 0, stream>>>(target, W_ys, b_gs, ysp, B_ * NL_, H4_, CC_, H4_, 1);
  }
  (void)hipMemsetAsync(sdec, 0, (size_t)(2 * B_ * H_ + B_ * T_) * sizeof(float), stream);

  // ---- decoder steps (5 launches each; output projection deferred) ----
  for (int step = 0; step < NL_; step++) {
    float* zdst = (step == 0) ? z0buf : (ysp + (size_t)(step - 1) * BH);
    dec_f1<<<564, 256, 0, stream>>>(alpha, conv_w, conv, sdec, W_se, sebuf);
    att_e<<<800, 256, 0, stream>>>(sebuf, he, conv, W_fe, W_ee, ebuf);
    att_sg<<<64, 256, 0, stream>>>(ebuf, lengths, hb, alpha, gvec);
    dec_f4<<<160, 256, 0, stream>>>(gvec, sdec, W_gy, W_sy, b_gy, zdst,
                                    W_ss, W_gs, ysp + (size_t)step * B_ * H4_, rec);
    dec_f5<<<32, 256, 0, stream>>>(rec, sdec, cdec);
  }

  // ---- batched output projection (two remapped GEMMs) ----
  {
    // steps 1..99: A row m=(s-1)*16+b -> out row (m&15)*100+(m>>4)+1
    dim3 g1((CC_ + GBN - 1) / GBN, ((NL_ - 1) * B_ + GBM - 1) / GBM);  // (40, 13)
    gemm_mfma<<<g1, 256, 0, stream>>>(ysp, W_yy, b_yy, out,
                                      (NL_ - 1) * B_, CC_, H_, CC_, 2);
    // step 0: A row m=b -> out row m*100
    dim3 g0((CC_ + GBN - 1) / GBN, 1);  // (40, 1)
    gemm_mfma<<<g0, 256, 0, stream>>>(z0buf, W_yy, b_yy, out,
                                      B_, CC_, H_, CC_, 3);
  }
}

// Round 17
// 43403.870 us; speedup vs baseline: 1.4227x; 1.0079x over previous
//
#include <hip/hip_runtime.h>
#include <math.h>

// Round 17: R16 + F4/F5 fusion (5 -> 4 launches/decoder step).
//   - sdec ping-pong (A/B) removes the WAR race; cdec element-wise in place
//   - rec buffer eliminated: lane-quad (4 lanes = 4 gates of one (b,jj))
//     computes gate dots, __shfl-exchanges, lane g0 does the LSTM update
// Encoder + everything else R16-identical.

#define T_    800
#define B_    16
#define FEAT_ 120
#define H_    512
#define H2_   1024
#define H4_   2048
#define CC_   5000
#define NL_   100
#define CH_   25
#define NCH_  32
#define HPAD  536

typedef __attribute__((ext_vector_type(8))) short bf16x8;
typedef __attribute__((ext_vector_type(4))) float f32x4;

__device__ __forceinline__ void coh_store_f32(float* p, float v) {
  asm volatile("global_store_dword %0, %1, off sc0 sc1"
               :: "v"(p), "v"(v) : "memory");
}
__device__ __forceinline__ void coh_load8_f4(
    const float* p0, const float* p1, const float* p2, const float* p3,
    const float* p4, const float* p5, const float* p6, const float* p7,
    f32x4* o)
{
  asm volatile(
      "global_load_dwordx4 %0, %8, off sc0 sc1\n\t"
      "global_load_dwordx4 %1, %9, off sc0 sc1\n\t"
      "global_load_dwordx4 %2, %10, off sc0 sc1\n\t"
      "global_load_dwordx4 %3, %11, off sc0 sc1\n\t"
      "global_load_dwordx4 %4, %12, off sc0 sc1\n\t"
      "global_load_dwordx4 %5, %13, off sc0 sc1\n\t"
      "global_load_dwordx4 %6, %14, off sc0 sc1\n\t"
      "global_load_dwordx4 %7, %15, off sc0 sc1\n\t"
      "s_waitcnt vmcnt(0)"
      : "=&v"(o[0]), "=&v"(o[1]), "=&v"(o[2]), "=&v"(o[3]),
        "=&v"(o[4]), "=&v"(o[5]), "=&v"(o[6]), "=&v"(o[7])
      : "v"(p0), "v"(p1), "v"(p2), "v"(p3), "v"(p4), "v"(p5), "v"(p6), "v"(p7)
      : "memory");
}

__device__ __forceinline__ unsigned short f2bf(float f) {
  unsigned u = __builtin_bit_cast(unsigned, f);
  u += 0x7FFFu + ((u >> 16) & 1u);
  return (unsigned short)(u >> 16);
}
__device__ __forceinline__ float bf2f(unsigned short s) {
  return __builtin_bit_cast(float, (unsigned)s << 16);
}

// ---------------- bf16 MFMA GEMM tile (with epilogue row remap) -----------
// rowmap: 0 identity | 1: (m%100)*16+m/100 | 2: (m&15)*100+(m>>4)+1 | 3: m*100
#define GBM 128
#define GBN 128
#define GBK 32
#define LDT 40

__device__ void mfma_gemm_tile(
    const float* __restrict__ A, const float* __restrict__ W,
    const float* __restrict__ bias, float* __restrict__ C,
    int M, int N, int K, int ldc, int bx, int by, int rowmap,
    unsigned short* As, unsigned short* Ws)
{
  const int tid = threadIdx.x;
  const int row0 = by * GBM, col0 = bx * GBN;
  const int lane = tid & 63, w = tid >> 6;
  const int wr = w >> 1, wc = w & 1;
  const int lm = lane & 15, lk8 = (lane >> 4) * 8;

  f32x4 acc[4][4];
#pragma unroll
  for (int i = 0; i < 4; i++)
#pragma unroll
    for (int j = 0; j < 4; j++) acc[i][j] = (f32x4)(0.f);

  const int sr = tid >> 1, skh = (tid & 1) * 16;

  for (int kt = 0; kt < K; kt += GBK) {
    {
      const int ar = row0 + sr;
      const int wrow = col0 + sr;
      unsigned short abuf[16], wbuf[16];
#pragma unroll
      for (int q = 0; q < 4; q++) {
        const int k0 = kt + skh + q * 4;
        float4 av = make_float4(0.f, 0.f, 0.f, 0.f);
        float4 wv = make_float4(0.f, 0.f, 0.f, 0.f);
        if (k0 + 4 <= K) {
          if (ar < M)   av = *(const float4*)(A + (size_t)ar * K + k0);
          if (wrow < N) wv = *(const float4*)(W + (size_t)wrow * K + k0);
        }
        abuf[q*4+0] = f2bf(av.x); abuf[q*4+1] = f2bf(av.y);
        abuf[q*4+2] = f2bf(av.z); abuf[q*4+3] = f2bf(av.w);
        wbuf[q*4+0] = f2bf(wv.x); wbuf[q*4+1] = f2bf(wv.y);
        wbuf[q*4+2] = f2bf(wv.z); wbuf[q*4+3] = f2bf(wv.w);
      }
      __syncthreads();
      *(uint4*)(As + sr * LDT + skh)     = *(uint4*)(abuf);
      *(uint4*)(As + sr * LDT + skh + 8) = *(uint4*)(abuf + 8);
      *(uint4*)(Ws + sr * LDT + skh)     = *(uint4*)(wbuf);
      *(uint4*)(Ws + sr * LDT + skh + 8) = *(uint4*)(wbuf + 8);
      __syncthreads();
    }
    bf16x8 af[4], bfv[4];
#pragma unroll
    for (int mi = 0; mi < 4; mi++)
      af[mi] = *(const bf16x8*)(As + (wr * 64 + mi * 16 + lm) * LDT + lk8);
#pragma unroll
    for (int ni = 0; ni < 4; ni++)
      bfv[ni] = *(const bf16x8*)(Ws + (wc * 64 + ni * 16 + lm) * LDT + lk8);
#pragma unroll
    for (int mi = 0; mi < 4; mi++)
#pragma unroll
      for (int ni = 0; ni < 4; ni++)
        acc[mi][ni] = __builtin_amdgcn_mfma_f32_16x16x32_bf16(
            af[mi], bfv[ni], acc[mi][ni], 0, 0, 0);
  }
#pragma unroll
  for (int mi = 0; mi < 4; mi++) {
#pragma unroll
    for (int reg = 0; reg < 4; reg++) {
      const int row = row0 + wr * 64 + mi * 16 + (lane >> 4) * 4 + reg;
      if (row < M) {
        int orow = row;
        if (rowmap == 1)      orow = (row % 100) * 16 + row / 100;
        else if (rowmap == 2) orow = (row & 15) * 100 + (row >> 4) + 1;
        else if (rowmap == 3) orow = row * 100;
        float* crow = C + (size_t)orow * ldc;
#pragma unroll
        for (int ni = 0; ni < 4; ni++) {
          const int col = col0 + wc * 64 + ni * 16 + lm;
          if (col < N) crow[col] = acc[mi][ni][reg] + (bias ? bias[col] : 0.f);
        }
      }
    }
  }
}

__global__ __launch_bounds__(256) void gemm_mfma(
    const float* __restrict__ A, const float* __restrict__ W,
    const float* __restrict__ bias, float* __restrict__ C,
    int M, int N, int K, int ldc, int rowmap)
{
  __shared__ unsigned short As[GBM * LDT];
  __shared__ unsigned short Ws[GBN * LDT];
  mfma_gemm_tile(A, W, bias, C, M, N, K, ldc, blockIdx.x, blockIdx.y, rowmap,
                 As, Ws);
}

__global__ __launch_bounds__(256) void gemm_mfma_dual(
    const float* __restrict__ A0, const float* __restrict__ W0,
    const float* __restrict__ b0, float* __restrict__ C0,
    const float* __restrict__ A1, const float* __restrict__ W1,
    const float* __restrict__ b1, float* __restrict__ C1,
    int M, int N, int K, int ldc)
{
  __shared__ unsigned short As[GBM * LDT];
  __shared__ unsigned short Ws[GBN * LDT];
  if (blockIdx.z == 0)
    mfma_gemm_tile(A0, W0, b0, C0, M, N, K, ldc, blockIdx.x, blockIdx.y, 0, As, Ws);
  else
    mfma_gemm_tile(A1, W1, b1, C1, M, N, K, ldc, blockIdx.x, blockIdx.y, 0, As, Ws);
}

__global__ __launch_bounds__(256) void transpose_x(
    const float* __restrict__ x, float* __restrict__ xt)
{
  const int i = blockIdx.x * 256 + threadIdx.x;
  if (i >= T_ * B_ * FEAT_) return;
  const int f = i % FEAT_;
  const int r = i / FEAT_;
  const int b = r % B_;
  const int t = r / B_;
  xt[i] = x[((long)b * T_ + t) * FEAT_ + f];
}

// ---------------- fused: compact-MFMA recurrence + next-chunk GEMM (R12) ---
__global__ __launch_bounds__(256, 1) void lstm_fused(
    const float* __restrict__ gxF, const float* __restrict__ gxB,
    float* __restrict__ gxFn, float* __restrict__ gxBn,
    const float* __restrict__ inbF, const float* __restrict__ inbB,
    const float* __restrict__ WihF_, const float* __restrict__ WihB_,
    const float* __restrict__ bF_, const float* __restrict__ bB_, int Kin,
    float* __restrict__ hg0, float* __restrict__ hg1,
    float* __restrict__ cg, float* __restrict__ outb,
    const float* __restrict__ WhhF, const float* __restrict__ WhhB,
    const int* __restrict__ lengths, int s0, int pbase,
    unsigned* __restrict__ bar)
{
  __shared__ unsigned short h_hi[16][HPAD];
  __shared__ unsigned short h_lo[16][HPAD];
  __shared__ float gl[128 * 16];
  __shared__ float c_l[512];
  __shared__ int   len_l[16];
  __shared__ unsigned short As[GBM * LDT];
  __shared__ unsigned short Ws[GBN * LDT];

  if (blockIdx.x >= 32) {
    if (inbF == nullptr) return;
    const int g = blockIdx.x - 32;
    const int bx = g & 15, by = (g >> 4) & 3, bz = g >> 6;
    if (bz == 0)
      mfma_gemm_tile(inbF, WihF_, bF_, gxFn, CH_ * B_, H4_, Kin, H4_, bx, by, 0, As, Ws);
    else
      mfma_gemm_tile(inbB, WihB_, bB_, gxBn, CH_ * B_, H4_, Kin, H4_, bx, by, 0, As, Ws);
    return;
  }

  const int wg  = blockIdx.x;
  const int dir = wg >> 4;
  const int m   = wg & 15;
  const int tid = threadIdx.x;
  const int lane = tid & 63, w = tid >> 6;
  const int lrow = lane & 15, lko = (lane >> 4) * 8;

  if (tid < 16) len_l[tid] = lengths[tid];
  {
    const int eA = tid, eB = tid + 256;
    c_l[eA] = cg[(dir * 16 + (eA & 15)) * 512 + m * 32 + (eA >> 4)];
    c_l[eB] = cg[(dir * 16 + (eB & 15)) * 512 + m * 32 + (eB >> 4)];
  }

  const float* Whh = dir ? WhhB : WhhF;
  bf16x8 whi[2][16], wlo[2][16];
#pragma unroll
  for (int rt = 0; rt < 2; rt++) {
    const int row128 = (w * 2 + rt) * 16 + lrow;
    const int g = row128 >> 5, jj = row128 & 31;
    const float* wr = Whh + (size_t)(g * 512 + m * 32 + jj) * 512 + lko;
#pragma unroll
    for (int kt = 0; kt < 16; kt++) {
      unsigned short h8[8], l8[8];
#pragma unroll
      for (int i = 0; i < 8; i++) {
        const float v = wr[kt * 32 + i];
        h8[i] = f2bf(v);
        l8[i] = f2bf(v - bf2f(h8[i]));
      }
      whi[rt][kt] = *(bf16x8*)h8;
      wlo[rt][kt] = *(bf16x8*)l8;
    }
  }
  __syncthreads();

  unsigned* bcnt = bar + dir * 32;

  const int b0  = tid & 15;
  const int jjA = tid >> 4;
  const int jjB = jjA + 16;
  const int gb_ = tid >> 4;
  const int gk0 = (tid & 15) * 32;

  for (int ls = 0; ls < CH_; ls++) {
    const int s = s0 + ls;
    const int lt = dir ? (CH_ - 1 - ls) : ls;
    const float* gxp = (dir ? gxB : gxF) + ((size_t)lt * 16 + b0) * 2048 + m * 32;
    float ga[4], gb[4];
#pragma unroll
    for (int g = 0; g < 4; g++) { ga[g] = gxp[g * 512 + jjA]; gb[g] = gxp[g * 512 + jjB]; }

    if (s == 0) {
      const uint4 z = make_uint4(0, 0, 0, 0);
#pragma unroll
      for (int o = 0; o < 4; o++) {
        *(uint4*)&h_hi[gb_][gk0 + o * 8] = z;
        *(uint4*)&h_lo[gb_][gk0 + o * 8] = z;
      }
    } else {
      const float* hsrc = ((s & 1) ? hg1 : hg0) + (dir * 16 + gb_) * 512 + gk0;
      f32x4 hv[8];
      coh_load8_f4(hsrc, hsrc + 4, hsrc + 8, hsrc + 12,
                   hsrc + 16, hsrc + 20, hsrc + 24, hsrc + 28, hv);
      unsigned short sh[32], sl[32];
#pragma unroll
      for (int q = 0; q < 8; q++)
#pragma unroll
        for (int i = 0; i < 4; i++) {
          const float v = hv[q][i];
          const unsigned short hh = f2bf(v);
          sh[q * 4 + i] = hh;
          sl[q * 4 + i] = f2bf(v - bf2f(hh));
        }
#pragma unroll
      for (int o = 0; o < 4; o++) {
        *(uint4*)&h_hi[gb_][gk0 + o * 8] = *(uint4*)(sh + o * 8);
        *(uint4*)&h_lo[gb_][gk0 + o * 8] = *(uint4*)(sl + o * 8);
      }
    }
    __syncthreads();

    f32x4 acc[2];
    acc[0] = (f32x4)(0.f); acc[1] = (f32x4)(0.f);
#pragma unroll
    for (int kt = 0; kt < 16; kt++) {
      const bf16x8 bh = *(const bf16x8*)&h_hi[lrow][kt * 32 + lko];
      const bf16x8 bl = *(const bf16x8*)&h_lo[lrow][kt * 32 + lko];
#pragma unroll
      for (int rt = 0; rt < 2; rt++) {
        acc[rt] = __builtin_amdgcn_mfma_f32_16x16x32_bf16(whi[rt][kt], bh, acc[rt], 0, 0, 0);
        acc[rt] = __builtin_amdgcn_mfma_f32_16x16x32_bf16(wlo[rt][kt], bh, acc[rt], 0, 0, 0);
        acc[rt] = __builtin_amdgcn_mfma_f32_16x16x32_bf16(whi[rt][kt], bl, acc[rt], 0, 0, 0);
      }
    }
#pragma unroll
    for (int rt = 0; rt < 2; rt++) {
      const int rbase = (w * 2 + rt) * 16 + (lane >> 4) * 4;
#pragma unroll
      for (int r = 0; r < 4; r++)
        gl[(rbase + r) * 16 + lrow] = acc[rt][r];
    }
    __syncthreads();

    const int t = dir ? (T_ - 1 - s) : s;
    const bool mk = t < len_l[b0];
    float houtA, houtB, hnA, hnB;
    {
      const float gi = gl[(0 * 32 + jjA) * 16 + b0] + ga[0];
      const float gf = gl[(1 * 32 + jjA) * 16 + b0] + ga[1];
      const float gc = gl[(2 * 32 + jjA) * 16 + b0] + ga[2];
      const float go = gl[(3 * 32 + jjA) * 16 + b0] + ga[3];
      const float iv = 1.f / (1.f + expf(-gi));
      const float fv = 1.f / (1.f + expf(-gf));
      const float gv = tanhf(gc);
      const float ov = 1.f / (1.f + expf(-go));
      const float c_old = c_l[tid];
      const float h_old = bf2f(h_hi[b0][m * 32 + jjA]) + bf2f(h_lo[b0][m * 32 + jjA]);
      const float cn = fv * c_old + iv * gv;
      hnA = ov * tanhf(cn);
      c_l[tid] = mk ? cn : c_old;
      houtA = mk ? hnA : h_old;
    }
    {
      const float gi = gl[(0 * 32 + jjB) * 16 + b0] + gb[0];
      const float gf = gl[(1 * 32 + jjB) * 16 + b0] + gb[1];
      const float gc = gl[(2 * 32 + jjB) * 16 + b0] + gb[2];
      const float go = gl[(3 * 32 + jjB) * 16 + b0] + gb[3];
      const float iv = 1.f / (1.f + expf(-gi));
      const float fv = 1.f / (1.f + expf(-gf));
      const float gv = tanhf(gc);
      const float ov = 1.f / (1.f + expf(-go));
      const float c_old = c_l[tid + 256];
      const float h_old = bf2f(h_hi[b0][m * 32 + jjB]) + bf2f(h_lo[b0][m * 32 + jjB]);
      const float cn = fv * c_old + iv * gv;
      hnB = ov * tanhf(cn);
      c_l[tid + 256] = mk ? cn : c_old;
      houtB = mk ? hnB : h_old;
    }
    {
      float* hdst = ((s & 1) ? hg0 : hg1) + (dir * 16 + b0) * 512 + m * 32;
      coh_store_f32(&hdst[jjA], houtA);
      coh_store_f32(&hdst[jjB], houtB);
    }
    asm volatile("s_waitcnt vmcnt(0)" ::: "memory");
    __syncthreads();
    if (ls != CH_ - 1 && tid == 0) {
      __hip_atomic_fetch_add(bcnt, 1u, __ATOMIC_RELAXED, __HIP_MEMORY_SCOPE_AGENT);
      const unsigned tgt = (unsigned)(pbase + ls + 1) * 16u;
      long tries = 0;
      while (__hip_atomic_load(bcnt, __ATOMIC_RELAXED,
                               __HIP_MEMORY_SCOPE_AGENT) < tgt) {
        if (++tries > (1L << 22)) break;  // fail loud, never hang
      }
    }
    __syncthreads();
    outb[((size_t)t * 16 + b0) * H2_ + dir * 512 + m * 32 + jjA] = mk ? hnA : 0.f;
    outb[((size_t)t * 16 + b0) * H2_ + dir * 512 + m * 32 + jjB] = mk ? hnB : 0.f;
  }
  {
    const int eA = tid, eB = tid + 256;
    cg[(dir * 16 + (eA & 15)) * 512 + m * 32 + (eA >> 4)] = c_l[eA];
    cg[(dir * 16 + (eB & 15)) * 512 + m * 32 + (eB >> 4)] = c_l[eB];
  }
}

// ---------------- consolidated decoder kernels ----------------
__device__ __forceinline__ float dot512(const float* s, const float* w) {
  float acc = 0.f;
#pragma unroll 4
  for (int k = 0; k < 512; k += 4) {
    float4 sv = *(const float4*)(s + k);
    float4 wv = *(const float4*)(w + k);
    acc = fmaf(sv.x, wv.x, acc); acc = fmaf(sv.y, wv.y, acc);
    acc = fmaf(sv.z, wv.z, acc); acc = fmaf(sv.w, wv.w, acc);
  }
  return acc;
}
__device__ __forceinline__ float dot1024(const float* s, const float* w) {
  float acc = 0.f;
#pragma unroll 4
  for (int k = 0; k < 1024; k += 4) {
    float4 sv = *(const float4*)(s + k);
    float4 wv = *(const float4*)(w + k);
    acc = fmaf(sv.x, wv.x, acc); acc = fmaf(sv.y, wv.y, acc);
    acc = fmaf(sv.z, wv.z, acc); acc = fmaf(sv.w, wv.w, acc);
  }
  return acc;
}

// F1: wg<500 conv ; wg>=500 se-projection
__global__ __launch_bounds__(256) void dec_f1(
    const float* __restrict__ alpha, const float* __restrict__ cw,
    float* __restrict__ conv,
    const float* __restrict__ sdec, const float* __restrict__ W_se,
    float* __restrict__ sebuf)
{
  const int wg = blockIdx.x, tid = threadIdx.x;
  if (wg < 500) {
    const int idx = wg * 256 + tid;
    if (idx >= B_ * 10 * T_) return;
    const int t = idx % T_;
    const int f = (idx / T_) % 10;
    const int b = idx / (10 * T_);
    const float* a = alpha + b * T_;
    const float* w = cw + f * 100;
    float acc = 0.f;
    const int k0 = (50 - t) > 0 ? (50 - t) : 0;
    const int k1 = (T_ + 50 - t) < 100 ? (T_ + 50 - t) : 100;
    for (int k = k0; k < k1; k++) acc = fmaf(a[t + k - 50], w[k], acc);
    conv[idx] = acc;
  } else {
    const int idx = (wg - 500) * 256 + tid;
    const int b = idx & 15, n = idx >> 4;
    sebuf[(size_t)b * H2_ + n] = dot512(sdec + (size_t)b * H_, W_se + (size_t)n * H_);
  }
}

__global__ __launch_bounds__(256) void att_e(
    const float* __restrict__ se, const float* __restrict__ he,
    const float* __restrict__ conv, const float* __restrict__ W_fe,
    const float* __restrict__ W_ee, float* __restrict__ e)
{
  __shared__ float wfe[10240];
  __shared__ float ses[1024];
  __shared__ float wee[1024];
  __shared__ float red[4];
  const int wg = blockIdx.x;
  const int b = wg / 50, t0 = (wg % 50) * 16;
  const int tid = threadIdx.x;
  for (int i = tid; i < 10240; i += 256) wfe[i] = W_fe[i];
  for (int i = tid; i < 1024; i += 256) {
    ses[i] = se[b * H2_ + i];
    wee[i] = W_ee[i];
  }
  __syncthreads();
  for (int tt = 0; tt < 16; tt++) {
    const int t = t0 + tt;
    float cv[10];
#pragma unroll
    for (int f = 0; f < 10; f++) cv[f] = conv[(b * 10 + f) * T_ + t];
    const float* hrow = he + ((long)t * B_ + b) * H2_;
    float part = 0.f;
#pragma unroll
    for (int q = 0; q < 4; q++) {
      const int d = tid + q * 256;
      float loc = 0.f;
      const float* wf = &wfe[d * 10];
#pragma unroll
      for (int f = 0; f < 10; f++) loc = fmaf(cv[f], wf[f], loc);
      const float val = tanhf(ses[d] + hrow[d] + loc);
      part = fmaf(val, wee[d], part);
    }
#pragma unroll
    for (int off = 32; off; off >>= 1) part += __shfl_down(part, off);
    if ((tid & 63) == 0) red[tid >> 6] = part;
    __syncthreads();
    if (tid == 0) e[b * T_ + t] = red[0] + red[1] + red[2] + red[3];
    __syncthreads();
  }
}

// F3: 64 WGs = (b, d-group). Redundant per-WG softmax in LDS, then g-dot.
__global__ __launch_bounds__(256) void att_sg(
    const float* __restrict__ e, const int* __restrict__ lengths,
    const float* __restrict__ hb, float* __restrict__ alpha,
    float* __restrict__ g)
{
  __shared__ float al[800];
  __shared__ float red[4];
  __shared__ float bc, bc2;
  const int wg = blockIdx.x;
  const int b = wg >> 2, dg = wg & 3;
  const int tid = threadIdx.x;
  const int len = lengths[b];
  float v[4];
  float mx = -1e30f;
#pragma unroll
  for (int q = 0; q < 4; q++) {
    const int t = tid + q * 256;
    v[q] = (t < T_) ? e[b * T_ + t] : -1e30f;
    mx = fmaxf(mx, v[q]);
  }
#pragma unroll
  for (int off = 32; off; off >>= 1) mx = fmaxf(mx, __shfl_down(mx, off));
  if ((tid & 63) == 0) red[tid >> 6] = mx;
  __syncthreads();
  if (tid == 0) bc = fmaxf(fmaxf(red[0], red[1]), fmaxf(red[2], red[3]));
  __syncthreads();
  const float m = bc;
  float ex[4];
  float s = 0.f;
#pragma unroll
  for (int q = 0; q < 4; q++) {
    const int t = tid + q * 256;
    ex[q] = (t < T_ && t < len) ? expf(v[q] - m) : 0.f;
    s += ex[q];
  }
#pragma unroll
  for (int off = 32; off; off >>= 1) s += __shfl_down(s, off);
  __syncthreads();
  if ((tid & 63) == 0) red[tid >> 6] = s;
  __syncthreads();
  if (tid == 0) bc2 = red[0] + red[1] + red[2] + red[3];
  __syncthreads();
  const float inv = 1.f / bc2;
#pragma unroll
  for (int q = 0; q < 4; q++) {
    const int t = tid + q * 256;
    if (t < T_) al[t] = ex[q] * inv;
  }
  __syncthreads();
  if (dg == 0) {
#pragma unroll
    for (int q = 0; q < 4; q++) {
      const int t = tid + q * 256;
      if (t < T_) alpha[b * T_ + t] = al[t];
    }
  }
  const int d = dg * 256 + tid;
  const float* hp = hb + (size_t)b * H2_ + d;
  float acc = 0.f;
#pragma unroll 8
  for (int t = 0; t < T_; t++)
    acc = fmaf(al[t], hp[(size_t)t * B_ * H2_], acc);
  g[b * H2_ + d] = acc;
}

// F45: wg<32 z (tanh proj -> zdst) ; wg in [32,160): rec dots (lane-quad =
// 4 gates of one (b,jj)) + shfl exchange + LSTM update (lane g0 writes).
__global__ __launch_bounds__(256) void dec_f45(
    const float* __restrict__ gvec, const float* __restrict__ sd_cur,
    const float* __restrict__ W_gy, const float* __restrict__ W_sy,
    const float* __restrict__ b_gy, float* __restrict__ zdst,
    const float* __restrict__ W_ss, const float* __restrict__ W_gs,
    const float* __restrict__ pre, float* __restrict__ sd_nxt,
    float* __restrict__ cdec)
{
  const int wg = blockIdx.x, tid = threadIdx.x;
  if (wg < 32) {
    const int idx = wg * 256 + tid;             // 8192 = B * H
    const int b = idx & 15, n = idx >> 4;
    float acc = b_gy[n];
    acc += dot1024(gvec + (size_t)b * H2_, W_gy + (size_t)n * H2_);
    acc += dot512(sd_cur + (size_t)b * H_, W_sy + (size_t)n * H_);
    zdst[(size_t)b * H_ + n] = tanhf(acc);
  } else {
    const int lin = (wg - 32) * 256 + tid;      // 32768 = B * H * 4
    const int g  = lin & 3;
    const int b  = (lin >> 2) & 15;
    const int jj = lin >> 6;                    // 0..511
    const int r  = jj + (g << 9);               // gate row in [0,2048)
    float acc = pre[(size_t)b * H4_ + r];
    acc += dot512(sd_cur + (size_t)b * H_, W_ss + (size_t)r * H_);
    acc += dot1024(gvec + (size_t)b * H2_, W_gs + (size_t)r * H2_);
    // quad exchange (lanes base..base+3 hold gates i,f,c,o of same (b,jj))
    const int base = (tid & 63) & ~3;
    const float gi = __shfl(acc, base + 0);
    const float gf = __shfl(acc, base + 1);
    const float gc = __shfl(acc, base + 2);
    const float go = __shfl(acc, base + 3);
    if (g == 0) {
      const int idx = b * H_ + jj;
      const float iv = tanhf(gi * 0.5f) * 0.5f + 0.5f;
      const float fv = tanhf(gf * 0.5f) * 0.5f + 0.5f;
      const float cgv = tanhf(gc);
      const float ov = tanhf(go * 0.5f) * 0.5f + 0.5f;
      const float cn = fv * cdec[idx] + iv * cgv;
      const float sn = ov * tanhf(cn);
      cdec[idx] = cn;
      sd_nxt[idx] = sn;
    }
  }
}

extern "C" void kernel_launch(void* const* d_in, const int* in_sizes, int n_in,
                              void* d_out, int out_size, void* d_ws, size_t ws_size,
                              hipStream_t stream)
{
  const float* x       = (const float*)d_in[0];
  const int*   lengths = (const int*)  d_in[1];
  const float* target  = (const float*)d_in[2];
  const float* Wih0    = (const float*)d_in[3];
  const float* Whh0    = (const float*)d_in[4];
  const float* b0      = (const float*)d_in[5];
  const float* WihL    = (const float*)d_in[6];
  const float* WhhL    = (const float*)d_in[7];
  const float* bL      = (const float*)d_in[8];
  const float* W_se    = (const float*)d_in[9];
  const float* W_he    = (const float*)d_in[10];
  const float* b_he    = (const float*)d_in[11];
  const float* W_ee    = (const float*)d_in[12];
  const float* conv_w  = (const float*)d_in[13];
  const float* W_fe    = (const float*)d_in[14];
  const float* W_sy    = (const float*)d_in[15];
  const float* W_gy    = (const float*)d_in[16];
  const float* b_gy    = (const float*)d_in[17];
  const float* W_yy    = (const float*)d_in[18];
  const float* b_yy    = (const float*)d_in[19];
  const float* W_ys    = (const float*)d_in[20];
  const float* W_ss    = (const float*)d_in[21];
  const float* W_gs    = (const float*)d_in[22];
  const float* b_gs    = (const float*)d_in[23];
  float* out = (float*)d_out;

  // ---- workspace layout (~119 MB) ----
  const size_t CHB4 = (size_t)CH_ * B_ * H4_;
  const size_t BH   = (size_t)B_ * H_;
  float* bufA = (float*)d_ws;
  float* bufB = bufA + (size_t)T_ * B_ * H2_;
  float* gxc0 = bufB + (size_t)T_ * B_ * H2_;
  float* gxc1 = gxc0 + 2 * CHB4;
  float* he   = bufB;
  float* ysp  = gxc0;                    // [NL][B][H4] step-major (4*CHB4)
  float* st   = gxc1 + 2 * CHB4;
  float* hg0  = st;
  float* hg1  = hg0 + 2 * B_ * H_;
  float* cg   = hg1 + 2 * B_ * H_;
  float* sdecA= cg + 2 * B_ * H_;
  float* sdecB= sdecA + B_ * H_;
  float* cdec = sdecB + B_ * H_;
  float* alpha= cdec + B_ * H_;
  float* conv = alpha + B_ * T_;
  float* ebuf = conv + B_ * 10 * T_;
  float* sebuf= ebuf + B_ * T_;
  float* gvec = sebuf + B_ * H2_;
  unsigned* bar = (unsigned*)(gvec + B_ * H2_ + 32);
  float* z0buf = (float*)(bar + 768);    // [B][H] for step 0 (32KB)

  (void)hipMemsetAsync(bar, 0, 2048, stream);  // once; monotonic thereafter

  // ---- encoder (R12 verbatim) ----
  transpose_x<<<(T_ * B_ * FEAT_ + 255) / 256, 256, 0, stream>>>(x, bufA);

  float* inb  = bufA;
  float* outb = bufB;
  float* gx[2] = {gxc0, gxc1};
  for (int l = 0; l < 4; l++) {
    const int Kin = (l == 0) ? FEAT_ : H2_;
    const float *WihF, *WihB, *WhhF, *WhhB, *bF, *bB;
    if (l == 0) {
      WihF = Wih0;                 WihB = Wih0 + (size_t)H4_ * FEAT_;
      WhhF = Whh0;                 WhhB = Whh0 + (size_t)H4_ * H_;
      bF = b0;                     bB = b0 + H4_;
    } else {
      const size_t o = (size_t)(l - 1) * 2;
      WihF = WihL + o * H4_ * H2_; WihB = WihF + (size_t)H4_ * H2_;
      WhhF = WhhL + o * H4_ * H_;  WhhB = WhhF + (size_t)H4_ * H_;
      bF = bL + o * H4_;           bB = bF + H4_;
    }
    (void)hipMemsetAsync(hg0, 0, (size_t)3 * 2 * B_ * H_ * sizeof(float), stream);
    {
      dim3 gg(H4_ / GBN, (CH_ * B_ + GBM - 1) / GBM, 2);
      gemm_mfma_dual<<<gg, 256, 0, stream>>>(
          inb, WihF, bF, gx[0],
          inb + (size_t)(T_ - CH_) * B_ * Kin, WihB, bB, gx[0] + CHB4,
          CH_ * B_, H4_, Kin, H4_);
    }
    for (int c = 0; c < NCH_; c++) {
      const int cur = c & 1, nxt = cur ^ 1;
      const bool hasNext = (c + 1 < NCH_);
      const float* inbFn = hasNext ? inb + (size_t)(c + 1) * CH_ * B_ * Kin : nullptr;
      const float* inbBn = hasNext ? inb + (size_t)(T_ - (c + 2) * CH_) * B_ * Kin : nullptr;
      lstm_fused<<<160, 256, 0, stream>>>(
          gx[cur], gx[cur] + CHB4, gx[nxt], gx[nxt] + CHB4,
          inbFn, inbBn, WihF, WihB, bF, bB, Kin,
          hg0, hg1, cg, outb, WhhF, WhhB, lengths,
          c * CH_, (l * NCH_ + c) * (CH_ - 1), bar);
    }
    float* tmp = inb; inb = outb; outb = tmp;
  }
  float* hb = inb;

  // ---- decoder precompute ----
  {
    dim3 ghe(H2_ / GBN, (T_ * B_) / GBM);
    gemm_mfma<<<ghe, 256, 0, stream>>>(hb, W_he, b_he, he, T_ * B_, H2_, H2_, H2_, 0);
    dim3 gys(H4_ / GBN, (B_ * NL_ + GBM - 1) / GBM);
    gemm_mfma<<<gys, 256, 0, stream>>>(target, W_ys, b_gs, ysp, B_ * NL_, H4_, CC_, H4_, 1);
  }
  (void)hipMemsetAsync(sdecA, 0, (size_t)(3 * B_ * H_ + B_ * T_) * sizeof(float), stream);

  // ---- decoder steps (4 launches each) ----
  for (int step = 0; step < NL_; step++) {
    float* sdc = (step & 1) ? sdecB : sdecA;
    float* sdn = (step & 1) ? sdecA : sdecB;
    float* zdst = (step == 0) ? z0buf : (ysp + (size_t)(step - 1) * BH);
    dec_f1<<<564, 256, 0, stream>>>(alpha, conv_w, conv, sdc, W_se, sebuf);
    att_e<<<800, 256, 0, stream>>>(sebuf, he, conv, W_fe, W_ee, ebuf);
    att_sg<<<64, 256, 0, stream>>>(ebuf, lengths, hb, alpha, gvec);
    dec_f45<<<160, 256, 0, stream>>>(gvec, sdc, W_gy, W_sy, b_gy, zdst,
                                     W_ss, W_gs, ysp + (size_t)step * B_ * H4_,
                                     sdn, cdec);
  }

  // ---- batched output projection (two remapped GEMMs) ----
  {
    dim3 g1((CC_ + GBN - 1) / GBN, ((NL_ - 1) * B_ + GBM - 1) / GBM);
    gemm_mfma<<<g1, 256, 0, stream>>>(ysp, W_yy, b_yy, out,
                                      (NL_ - 1) * B_, CC_, H_, CC_, 2);
    dim3 g0((CC_ + GBN - 1) / GBN, 1);
    gemm_mfma<<<g0, 256, 0, stream>>>(z0buf, W_yy, b_yy, out,
                                      B_, CC_, H_, CC_, 3);
  }
}